// Round 1
// baseline (1564.411 us; speedup 1.0000x reference)
//
#include <hip/hip_runtime.h>

// Problem constants (B=1)
constexpr int kN1 = 512;    // queries / local preds
constexpr int kN2 = 2048;   // keys
constexpr int kC  = 1024;   // channels
constexpr int kH  = 8;      // heads
constexpr int kHD = 128;    // head dim
constexpr int kC2 = 2048;   // 2C
constexpr int kC3 = 3072;   // 3C

// ---------------------------------------------------------------------------
// Generic tiled fp32 GEMM: C[z] = alpha * (A[z] @ B[z](^T)) * colScale? + bias?
// 64x64 tile, BK=16, 256 threads, 4x4 accum per thread. All dims assumed
// multiples of 64 (M,N) and 16 (K) -- true for every call in this pipeline.
// ---------------------------------------------------------------------------
template<bool TRANSB, bool COLSCALE, bool BIAS>
__global__ __launch_bounds__(256)
void gemm_kernel(int M, int N, int K,
                 const float* __restrict__ A, int lda, long sAz,
                 const float* __restrict__ B, int ldb, long sBz,
                 float* __restrict__ C, int ldc, long sCz,
                 float alpha,
                 const float* __restrict__ colScale,
                 const float* __restrict__ bias)
{
    A += (long)blockIdx.z * sAz;
    B += (long)blockIdx.z * sBz;
    C += (long)blockIdx.z * sCz;
    __shared__ float As[16][68];   // +4 pad keeps float4 alignment, breaks conflicts
    __shared__ float Bs[16][68];
    const int tid = threadIdx.x;
    const int tm = (tid >> 4) << 2;     // 0..60
    const int tn = (tid & 15) << 2;     // 0..60
    const int m0 = blockIdx.y * 64;
    const int n0 = blockIdx.x * 64;
    const int lr = tid >> 2;            // 0..63 (tile row for A / B^T loads)
    const int lk = (tid & 3) << 2;      // 0,4,8,12

    float acc[4][4] = {};
    for (int k0 = 0; k0 < K; k0 += 16) {
        // A tile: 64 rows x 16 k, float4 per thread
        float4 va = *(const float4*)(A + (long)(m0 + lr) * lda + (k0 + lk));
        As[lk + 0][lr] = va.x;
        As[lk + 1][lr] = va.y;
        As[lk + 2][lr] = va.z;
        As[lk + 3][lr] = va.w;
        if (TRANSB) {
            // B is [N x K] row-major; need Bs[k][n]
            float4 vb = *(const float4*)(B + (long)(n0 + lr) * ldb + (k0 + lk));
            Bs[lk + 0][lr] = vb.x;
            Bs[lk + 1][lr] = vb.y;
            Bs[lk + 2][lr] = vb.z;
            Bs[lk + 3][lr] = vb.w;
        } else {
            // B is [K x N] row-major
            const int bk = tid >> 4;           // 0..15
            const int bn = (tid & 15) << 2;    // 0..60
            float4 vb = *(const float4*)(B + (long)(k0 + bk) * ldb + (n0 + bn));
            *(float4*)&Bs[bk][bn] = vb;
        }
        __syncthreads();
        #pragma unroll
        for (int kk = 0; kk < 16; ++kk) {
            const float4 a4 = *(const float4*)&As[kk][tm];
            const float4 b4 = *(const float4*)&Bs[kk][tn];
            const float av[4] = {a4.x, a4.y, a4.z, a4.w};
            const float bv[4] = {b4.x, b4.y, b4.z, b4.w};
            #pragma unroll
            for (int i = 0; i < 4; ++i)
                #pragma unroll
                for (int j = 0; j < 4; ++j)
                    acc[i][j] = fmaf(av[i], bv[j], acc[i][j]);
        }
        __syncthreads();
    }
    #pragma unroll
    for (int i = 0; i < 4; ++i) {
        float* crow = C + (long)(m0 + tm + i) * ldc;
        #pragma unroll
        for (int j = 0; j < 4; ++j) {
            const int n = n0 + tn + j;
            float v = acc[i][j] * alpha;
            if (COLSCALE) v *= colScale[n];
            if (BIAS) v += bias[n];
            crow[n] = v;
        }
    }
}

static void gemm(hipStream_t st, bool transB, int M, int N, int K,
                 const float* A, int lda, long sAz,
                 const float* B, int ldb, long sBz,
                 float* C, int ldc, long sCz, int Z,
                 float alpha, const float* colScale, const float* bias)
{
    dim3 g(N / 64, M / 64, Z), b(256);
    if (transB) {
        if (colScale)
            gemm_kernel<true, true, false><<<g, b, 0, st>>>(M, N, K, A, lda, sAz, B, ldb, sBz, C, ldc, sCz, alpha, colScale, nullptr);
        else
            gemm_kernel<true, false, false><<<g, b, 0, st>>>(M, N, K, A, lda, sAz, B, ldb, sBz, C, ldc, sCz, alpha, nullptr, nullptr);
    } else {
        if (bias)
            gemm_kernel<false, false, true><<<g, b, 0, st>>>(M, N, K, A, lda, sAz, B, ldb, sBz, C, ldc, sCz, alpha, nullptr, bias);
        else
            gemm_kernel<false, false, false><<<g, b, 0, st>>>(M, N, K, A, lda, sAz, B, ldb, sBz, C, ldc, sCz, alpha, nullptr, nullptr);
    }
}

// ---------------------------------------------------------------------------
// Per-(row,head) L2 normalization over 128 elems. One 128-thread block each.
// ---------------------------------------------------------------------------
__global__ __launch_bounds__(128)
void l2norm_kernel(const float* __restrict__ src, int lsrc, int soff,
                   float* __restrict__ dst, int ldst, int doff)
{
    const int b = blockIdx.x;        // row * 8 + head
    const int row = b >> 3, h = b & 7;
    const int t = threadIdx.x;
    const float v = src[(long)row * lsrc + soff + h * kHD + t];
    __shared__ float red[128];
    red[t] = v * v;
    __syncthreads();
    for (int s = 64; s > 0; s >>= 1) { if (t < s) red[t] += red[t + s]; __syncthreads(); }
    const float inv = rsqrtf(red[0]);
    dst[(long)row * ldst + doff + h * kHD + t] = v * inv;
}

// ---------------------------------------------------------------------------
// Row softmax over ncols (2048), in place. One 256-thread block per row.
// ---------------------------------------------------------------------------
__global__ __launch_bounds__(256)
void softmax_rows(float* __restrict__ S, int ncols)
{
    float* p = S + (long)blockIdx.x * ncols;
    const int t = threadIdx.x;
    __shared__ float red[256];
    float mx = -1e30f;
    for (int i = t; i < ncols; i += 256) mx = fmaxf(mx, p[i]);
    red[t] = mx; __syncthreads();
    for (int s = 128; s > 0; s >>= 1) { if (t < s) red[t] = fmaxf(red[t], red[t + s]); __syncthreads(); }
    mx = red[0]; __syncthreads();
    float sum = 0.f;
    for (int i = t; i < ncols; i += 256) { float e = expf(p[i] - mx); p[i] = e; sum += e; }
    red[t] = sum; __syncthreads();
    for (int s = 128; s > 0; s >>= 1) { if (t < s) red[t] += red[t + s]; __syncthreads(); }
    const float inv = 1.f / red[0];
    for (int i = t; i < ncols; i += 256) p[i] *= inv;
}

// ---------------------------------------------------------------------------
// attn = (softmax_cls + softmax_reg)/2 (into Scls); attnSum = mean over heads
// ---------------------------------------------------------------------------
__global__ __launch_bounds__(256)
void blend_kernel(float* __restrict__ Scls, const float* __restrict__ Sreg,
                  float* __restrict__ attnSum)
{
    const long idx = (long)blockIdx.x * 256 + threadIdx.x;   // over N1*N2
    const int q = (int)(idx / kN2), k = (int)(idx % kN2);
    float s = 0.f;
    #pragma unroll
    for (int h = 0; h < kH; ++h) {
        const long o = ((long)h * kN1 + q) * kN2 + k;
        const float a = 0.5f * (Scls[o] + Sreg[o]);
        Scls[o] = a;
        s += a;
    }
    attnSum[idx] = s * 0.125f;
}

// ---------------------------------------------------------------------------
// Copy V-half of kv rows [0,512) into cols [1024,2048) of the concat buffer.
// ---------------------------------------------------------------------------
__global__ __launch_bounds__(256)
void copy_xori(const float* __restrict__ kv, float* __restrict__ xcat)
{
    const int idx = blockIdx.x * 256 + threadIdx.x;   // over N1*C
    const int n = idx / kC, j = idx % kC;
    xcat[(long)n * kC2 + kC + j] = kv[(long)n * kC2 + kC + j];
}

// ---------------------------------------------------------------------------
// Round-2 weights. Per query row:
//   e_k = exp(attnSum_k - max); m = simS>0.75; mo = regS>0.99
//   sim_round2 = e*m / sum(e*m)        (softmax denom cancels in renorm)
//   obj_w      = e*m*mo / sum(e*m*mo)
// Writes sim_round2 over simS and obj_w over regS (read-before-write per elem).
// ---------------------------------------------------------------------------
__global__ __launch_bounds__(256)
void round2_kernel(const float* __restrict__ attnSum,
                   float* __restrict__ simS, float* __restrict__ regS)
{
    const int q = blockIdx.x;
    const float* as = attnSum + (long)q * kN2;
    float* sp = simS + (long)q * kN2;
    float* rp = regS + (long)q * kN2;
    const int t = threadIdx.x;
    __shared__ float e[kN2];
    __shared__ float red[256];
    float mx = -1e30f;
    for (int i = t; i < kN2; i += 256) mx = fmaxf(mx, as[i]);
    red[t] = mx; __syncthreads();
    for (int s = 128; s > 0; s >>= 1) { if (t < s) red[t] = fmaxf(red[t], red[t + s]); __syncthreads(); }
    mx = red[0]; __syncthreads();
    float s1 = 0.f, s2 = 0.f;
    for (int i = t; i < kN2; i += 256) {
        const float ev = expf(as[i] - mx);
        e[i] = ev;
        const float m  = sp[i] > 0.75f ? 1.f : 0.f;
        const float mo = rp[i] > 0.99f ? 1.f : 0.f;
        s1 += ev * m;
        s2 += ev * m * mo;
    }
    red[t] = s1; __syncthreads();
    for (int s = 128; s > 0; s >>= 1) { if (t < s) red[t] += red[t + s]; __syncthreads(); }
    s1 = red[0]; __syncthreads();
    red[t] = s2; __syncthreads();
    for (int s = 128; s > 0; s >>= 1) { if (t < s) red[t] += red[t + s]; __syncthreads(); }
    s2 = red[0]; __syncthreads();
    const float i1 = 1.f / s1, i2 = 1.f / s2;
    for (int i = t; i < kN2; i += 256) {
        const float m  = sp[i] > 0.75f ? 1.f : 0.f;
        const float mo = rp[i] > 0.99f ? 1.f : 0.f;
        const float ev = e[i];
        sp[i] = ev * m * i1;
        rp[i] = ev * m * mo * i2;
    }
}

extern "C" void kernel_launch(void* const* d_in, const int* in_sizes, int n_in,
                              void* d_out, int out_size, void* d_ws, size_t ws_size,
                              hipStream_t stream)
{
    const float* x_cls     = (const float*)d_in[0];
    const float* x_reg     = (const float*)d_in[1];
    const float* cls_score = (const float*)d_in[2];
    // d_in[3] fg_score: unused in the use_mask=False path
    const float* W_q_cls   = (const float*)d_in[4];
    const float* W_kv_cls  = (const float*)d_in[5];
    const float* W_q_reg   = (const float*)d_in[6];
    const float* W_kv_reg  = (const float*)d_in[7];
    const float* W_lin     = (const float*)d_in[8];
    const float* b_lin     = (const float*)d_in[9];
    const float* W_lin_reg = (const float*)d_in[10];
    const float* b_lin_reg = (const float*)d_in[11];
    float* out = (float*)d_out;
    float* ws  = (float*)d_ws;

    // Workspace layout (floats). Total = 33,554,432 floats = 128 MiB.
    float* kv_cls = ws;                        // [2048 x 2048]  (K half | V half)
    float* kv_reg = kv_cls + 4194304;
    float* vn_cls = kv_reg + 4194304;          // [2048 x 1024] per-head-normalized V
    float* vn_reg = vn_cls + 2097152;
    float* qn_cls = vn_reg + 2097152;          // [512 x 1024]
    float* qn_reg = qn_cls + 524288;
    float* S_cls  = qn_reg + 524288;           // [8 x 512 x 2048]
    float* S_reg  = S_cls + 8388608;           // [8 x 512 x 2048]
    float* simS   = S_reg + 8388608;           // [512 x 2048] raw v-sim/8 -> sim_round2
    float* regS   = simS + 1048576;            // [512 x 2048] raw v-sim/8 -> obj_w
    float* attnS  = regS + 1048576;            // [512 x 2048]
    float* xcat_cls = S_reg;                   // reuse S_reg region after blend
    float* xcat_reg = S_reg + 1048576;

    if (ws_size < (size_t)33554432 * sizeof(float)) return;  // constant per session

    // 1. Projections (W stored [in, out], row-major -> plain GEMM)
    gemm(stream, false, kN1, kC,  kC, x_cls, kC, 0, W_q_cls,  kC,  0, qn_cls, kC,  0, 1, 1.f, nullptr, nullptr);
    gemm(stream, false, kN1, kC,  kC, x_reg, kC, 0, W_q_reg,  kC,  0, qn_reg, kC,  0, 1, 1.f, nullptr, nullptr);
    gemm(stream, false, kN2, kC2, kC, x_cls, kC, 0, W_kv_cls, kC2, 0, kv_cls, kC2, 0, 1, 1.f, nullptr, nullptr);
    gemm(stream, false, kN2, kC2, kC, x_reg, kC, 0, W_kv_reg, kC2, 0, kv_reg, kC2, 0, 1, 1.f, nullptr, nullptr);

    // 2. L2 normalizations: q,k in place; v into vn buffers (raw v kept in kv)
    l2norm_kernel<<<kN1 * kH, 128, 0, stream>>>(qn_cls, kC,  0,  qn_cls, kC,  0);
    l2norm_kernel<<<kN1 * kH, 128, 0, stream>>>(qn_reg, kC,  0,  qn_reg, kC,  0);
    l2norm_kernel<<<kN2 * kH, 128, 0, stream>>>(kv_cls, kC2, 0,  kv_cls, kC2, 0);
    l2norm_kernel<<<kN2 * kH, 128, 0, stream>>>(kv_reg, kC2, 0,  kv_reg, kC2, 0);
    l2norm_kernel<<<kN2 * kH, 128, 0, stream>>>(kv_cls, kC2, kC, vn_cls, kC,  0);
    l2norm_kernel<<<kN2 * kH, 128, 0, stream>>>(kv_reg, kC2, kC, vn_reg, kC,  0);

    // 3. Raw v-v similarity, summed over heads / 8 == (vn[:512] @ vn^T) / 8
    gemm(stream, true, kN1, kN2, kC, vn_cls, kC, 0, vn_cls, kC, 0, simS, kN2, 0, 1, 0.125f, nullptr, nullptr);
    gemm(stream, true, kN1, kN2, kC, vn_reg, kC, 0, vn_reg, kC, 0, regS, kN2, 0, 1, 0.125f, nullptr, nullptr);

    // 4. Attention scores per head (batched over z): S = (q @ k^T) * 25 [* cs]
    gemm(stream, true, kN1, kN2, kHD, qn_cls, kC, kHD, kv_cls, kC2, kHD,
         S_cls, kN2, (long)kN1 * kN2, kH, 25.f, cls_score, nullptr);
    gemm(stream, true, kN1, kN2, kHD, qn_reg, kC, kHD, kv_reg, kC2, kHD,
         S_reg, kN2, (long)kN1 * kN2, kH, 25.f, nullptr, nullptr);

    // 5. Row softmax per (head, query)
    softmax_rows<<<kH * kN1, 256, 0, stream>>>(S_cls, kN2);
    softmax_rows<<<kH * kN1, 256, 0, stream>>>(S_reg, kN2);

    // 6. Blend + head-mean (attn lives in S_cls afterwards; S_reg becomes free)
    blend_kernel<<<(kN1 * kN2) / 256, 256, 0, stream>>>(S_cls, S_reg, attnS);

    // 7. x = attn @ v per head -> cols [0,1024) of concat buffers
    gemm(stream, false, kN1, kHD, kN2, S_cls, kN2, (long)kN1 * kN2,
         kv_cls + kC, kC2, kHD, xcat_cls, kC2, kHD, kH, 1.f, nullptr, nullptr);
    gemm(stream, false, kN1, kHD, kN2, S_cls, kN2, (long)kN1 * kN2,
         kv_reg + kC, kC2, kHD, xcat_reg, kC2, kHD, kH, 1.f, nullptr, nullptr);

    // 8. x_ori -> cols [1024,2048)
    copy_xori<<<(kN1 * kC) / 256, 256, 0, stream>>>(kv_cls, xcat_cls);
    copy_xori<<<(kN1 * kC) / 256, 256, 0, stream>>>(kv_reg, xcat_reg);

    // 9. Output linears straight into d_out cols [1024,3072)
    gemm(stream, false, kN1, kC2, kC2, xcat_cls, kC2, 0, W_lin, kC2, 0,
         out + kC, kC3, 0, 1, 1.f, nullptr, b_lin);
    gemm(stream, false, kN1, kC2, kC2, xcat_reg, kC2, 0, W_lin_reg, kC2, 0,
         out + (long)kN1 * kC3 + kC, kC3, 0, 1, 1.f, nullptr, b_lin_reg);

    // 10. Round-2 masked renormalized weights (in place over simS / regS)
    round2_kernel<<<kN1, 256, 0, stream>>>(attnS, simS, regS);

    // 11. ave features straight into d_out cols [0,1024)
    gemm(stream, false, kN1, kC, kN2, simS, kN2, 0, kv_cls + kC, kC2, 0,
         out, kC3, 0, 1, 1.f, nullptr, nullptr);
    gemm(stream, false, kN1, kC, kN2, regS, kN2, 0, kv_reg + kC, kC2, 0,
         out + (long)kN1 * kC3, kC3, 0, 1, 1.f, nullptr, nullptr);
}

// Round 2
// 886.355 us; speedup vs baseline: 1.7650x; 1.7650x over previous
//
#include <hip/hip_runtime.h>

// Problem constants (B=1)
constexpr int kN1 = 512;    // queries / local preds
constexpr int kN2 = 2048;   // keys
constexpr int kC  = 1024;   // channels
constexpr int kH  = 8;      // heads
constexpr int kHD = 128;    // head dim
constexpr int kC2 = 2048;   // 2C
constexpr int kC3 = 3072;   // 3C

typedef _Float16 half8 __attribute__((ext_vector_type(8)));
typedef _Float16 half4v __attribute__((ext_vector_type(4)));
typedef float f32x4 __attribute__((ext_vector_type(4)));

// async global->LDS, 16 B per lane; LDS dest is wave-uniform base + lane*16
#define GLD16(gptr, lptr) \
    __builtin_amdgcn_global_load_lds((const __attribute__((address_space(1))) void*)(gptr), \
                                     (__attribute__((address_space(3))) void*)(lptr), 16, 0, 0)

// ---------------------------------------------------------------------------
// fp16 NT MFMA GEMM: C[z] = alpha * (A[z] @ B[z]^T) [* colScale] [+ bias]
// A: [M x K] rows (lda elems), B: [N x K] rows (ldb elems), both _Float16.
// Tile 128x128, BK=32, 256 threads (4 waves, each 64x64 via 4x4 MFMAs of
// 16x16x32). LDS layout per tile: [kq 0..3][row 0..127][8 halfs] (16 B rows)
// -> conflict-free ds_read_b128 and matches global_load_lds lane order.
// Requires: M,N multiples of 128, K multiple of 32, lda/ldb/offsets mult of 8.
// ---------------------------------------------------------------------------
template<int OUT_HALF, int COLSCALE, int BIAS>
__global__ __launch_bounds__(256)
void hgemm_nt(int K,
              const _Float16* __restrict__ A, int lda, long sAz,
              const _Float16* __restrict__ B, int ldb, long sBz,
              void* __restrict__ Cv, int ldc, long sCz,
              float alpha,
              const float* __restrict__ colScale,
              const float* __restrict__ bias)
{
    __shared__ uint4 smem[1024];              // 16 KB: A tile 8 KB | B tile 8 KB
    char* ldsA = (char*)smem;
    char* ldsB = ldsA + 8192;
    const int tid = threadIdx.x;
    const int w = tid >> 6, l = tid & 63;
    const int m0 = blockIdx.y << 7, n0 = blockIdx.x << 7;
    const int wm = (w >> 1) << 6, wn = (w & 1) << 6;
    const int kq = l >> 4, lm = l & 15;

    A += (long)blockIdx.z * sAz;
    B += (long)blockIdx.z * sBz;

    // staging: wave w stages chunks w and w+4 (chunk = 64 rows x one 8-elem kq)
    const int skq = w >> 1;               // kq of chunk w; chunk w+4 -> skq+2
    const int sr0 = (w & 1) << 6;         // row base 0 / 64
    const _Float16* gA = A + (long)(m0 + sr0 + l) * lda + skq * 8;
    const _Float16* gB = B + (long)(n0 + sr0 + l) * ldb + skq * 8;
    char* lA0 = ldsA + skq * 2048 + sr0 * 16 + l * 16;
    char* lB0 = ldsB + skq * 2048 + sr0 * 16 + l * 16;

    f32x4 acc[4][4] = {};

    for (int k0 = 0; k0 < K; k0 += 32) {
        __syncthreads();                  // protect LDS from prior-iter readers
        GLD16(gA + k0,      lA0);
        GLD16(gA + k0 + 16, lA0 + 4096);
        GLD16(gB + k0,      lB0);
        GLD16(gB + k0 + 16, lB0 + 4096);
        __syncthreads();                  // drains vmcnt before reads
        half8 af[4], bfr[4];
        const char* pa = ldsA + kq * 2048 + (wm + lm) * 16;
        const char* pb = ldsB + kq * 2048 + (wn + lm) * 16;
        #pragma unroll
        for (int i = 0; i < 4; ++i) {
            af[i]  = *(const half8*)(pa + i * 256);
            bfr[i] = *(const half8*)(pb + i * 256);
        }
        #pragma unroll
        for (int mi = 0; mi < 4; ++mi)
            #pragma unroll
            for (int ni = 0; ni < 4; ++ni)
                acc[mi][ni] = __builtin_amdgcn_mfma_f32_16x16x32_f16(af[mi], bfr[ni], acc[mi][ni], 0, 0, 0);
    }

    // C/D layout: col = lane&15, row = (lane>>4)*4 + reg  [verified m89/m91]
    const int rbase = m0 + wm + kq * 4;
    #pragma unroll
    for (int mi = 0; mi < 4; ++mi) {
        #pragma unroll
        for (int ni = 0; ni < 4; ++ni) {
            const int col = n0 + wn + ni * 16 + lm;
            const float cs = COLSCALE ? colScale[col] : 1.f;
            const float bs = BIAS ? bias[col] : 0.f;
            #pragma unroll
            for (int r = 0; r < 4; ++r) {
                const long row = rbase + mi * 16 + r;
                float v = acc[mi][ni][r] * alpha;
                if (COLSCALE) v *= cs;
                if (BIAS) v += bs;
                const long off = (long)blockIdx.z * sCz + row * ldc + col;
                if (OUT_HALF) ((_Float16*)Cv)[off] = (_Float16)v;
                else          ((float*)Cv)[off] = v;
            }
        }
    }
}

static void hgemm(hipStream_t st, int M, int N, int K,
                  const _Float16* A, int lda, long sAz,
                  const _Float16* B, int ldb, long sBz,
                  void* C, int ldc, long sCz, int Z,
                  float alpha, const float* colScale, const float* bias, bool outHalf)
{
    dim3 g(N / 128, M / 128, Z), b(256);
    if (outHalf)
        hgemm_nt<1, 0, 0><<<g, b, 0, st>>>(K, A, lda, sAz, B, ldb, sBz, C, ldc, sCz, alpha, nullptr, nullptr);
    else if (colScale)
        hgemm_nt<0, 1, 0><<<g, b, 0, st>>>(K, A, lda, sAz, B, ldb, sBz, C, ldc, sCz, alpha, colScale, nullptr);
    else if (bias)
        hgemm_nt<0, 0, 1><<<g, b, 0, st>>>(K, A, lda, sAz, B, ldb, sBz, C, ldc, sCz, alpha, nullptr, bias);
    else
        hgemm_nt<0, 0, 0><<<g, b, 0, st>>>(K, A, lda, sAz, B, ldb, sBz, C, ldc, sCz, alpha, nullptr, nullptr);
}

// ---------------------------------------------------------------------------
// fp32 -> fp16 elementwise cast, 4 elems/thread
// ---------------------------------------------------------------------------
__global__ __launch_bounds__(256)
void cast_f2h(const float* __restrict__ s, _Float16* __restrict__ d, int n4)
{
    const int i = blockIdx.x * 256 + threadIdx.x;
    if (i < n4) {
        const float4 v = ((const float4*)s)[i];
        half4v o;
        o.x = (_Float16)v.x; o.y = (_Float16)v.y; o.z = (_Float16)v.z; o.w = (_Float16)v.w;
        ((half4v*)d)[i] = o;
    }
}

// ---------------------------------------------------------------------------
// Transpose-cast to fp16: dst[n][k] = src[k][n]. Grid (Ncols/32, Krows/32).
// ---------------------------------------------------------------------------
template<typename T>
__global__ __launch_bounds__(256)
void transpose_h(const T* __restrict__ src, int ldsrc, _Float16* __restrict__ dst, int lddst)
{
    __shared__ float t[32][33];
    const int n0 = blockIdx.x << 5, k0 = blockIdx.y << 5;
    const int tx = threadIdx.x & 31, ty = threadIdx.x >> 5;
    #pragma unroll
    for (int j = ty; j < 32; j += 8)
        t[j][tx] = (float)src[(size_t)(k0 + j) * ldsrc + n0 + tx];
    __syncthreads();
    #pragma unroll
    for (int j = ty; j < 32; j += 8)
        dst[(size_t)(n0 + j) * lddst + k0 + tx] = (_Float16)t[tx][j];
}

// ---------------------------------------------------------------------------
// Per-(row,head) L2 norm over 128 elems, fp16 in/out (fp32 math).
// ---------------------------------------------------------------------------
__global__ __launch_bounds__(128)
void headnorm(const _Float16* __restrict__ src, int ls, int so,
              _Float16* __restrict__ dst, int ld, int dof)
{
    const int b = blockIdx.x, row = b >> 3, h = b & 7, t = threadIdx.x;
    const float v = (float)src[(size_t)row * ls + so + h * kHD + t];
    __shared__ float red[128];
    red[t] = v * v; __syncthreads();
    for (int s = 64; s > 0; s >>= 1) { if (t < s) red[t] += red[t + s]; __syncthreads(); }
    dst[(size_t)row * ld + dof + h * kHD + t] = (_Float16)(v * rsqrtf(red[0]));
}

// ---------------------------------------------------------------------------
// Row softmax over 2048 cols, fp32 in place.
// ---------------------------------------------------------------------------
__global__ __launch_bounds__(256)
void softmax_rows(float* __restrict__ S)
{
    float* p = S + (long)blockIdx.x * kN2;
    const int t = threadIdx.x;
    __shared__ float red[256];
    float mx = -1e30f;
    for (int i = t; i < kN2; i += 256) mx = fmaxf(mx, p[i]);
    red[t] = mx; __syncthreads();
    for (int s = 128; s > 0; s >>= 1) { if (t < s) red[t] = fmaxf(red[t], red[t + s]); __syncthreads(); }
    mx = red[0]; __syncthreads();
    float sum = 0.f;
    for (int i = t; i < kN2; i += 256) { float e = expf(p[i] - mx); p[i] = e; sum += e; }
    red[t] = sum; __syncthreads();
    for (int s = 128; s > 0; s >>= 1) { if (t < s) red[t] += red[t + s]; __syncthreads(); }
    const float inv = 1.f / red[0];
    for (int i = t; i < kN2; i += 256) p[i] *= inv;
}

// ---------------------------------------------------------------------------
// attn = (S_cls + P_reg)/2 -> fp16 attn; attnS = mean over heads (fp32)
// ---------------------------------------------------------------------------
__global__ __launch_bounds__(256)
void blend_kernel(const float* __restrict__ Scls, const _Float16* __restrict__ Preg,
                  _Float16* __restrict__ attn, float* __restrict__ attnS)
{
    const long idx = (long)blockIdx.x * 256 + threadIdx.x;   // over N1*N2
    const int q = (int)(idx >> 11), k = (int)(idx & 2047);
    float s = 0.f;
    #pragma unroll
    for (int h = 0; h < kH; ++h) {
        const long o = ((long)h * kN1 + q) * kN2 + k;
        const float a = 0.5f * (Scls[o] + (float)Preg[o]);
        attn[o] = (_Float16)a;
        s += a;
    }
    attnS[idx] = s * 0.125f;
}

// ---------------------------------------------------------------------------
// x_ori: copy V-half of kv rows [0,512) into cols [1024,2048) of xcat (fp16)
// ---------------------------------------------------------------------------
__global__ __launch_bounds__(256)
void copy_xori(const _Float16* __restrict__ kvh, _Float16* __restrict__ xcat)
{
    const int i = blockIdx.x * 256 + threadIdx.x;   // over N1*C
    const int n = i >> 10, j = i & 1023;
    xcat[(size_t)n * kC2 + kC + j] = kvh[(size_t)n * kC2 + kC + j];
}

// ---------------------------------------------------------------------------
// Round-2 masked renormalized weights (softmax denom cancels), fp16 out.
// ---------------------------------------------------------------------------
__global__ __launch_bounds__(256)
void round2_kernel(const float* __restrict__ attnSum,
                   const float* __restrict__ simS, const float* __restrict__ regS,
                   _Float16* __restrict__ wcls, _Float16* __restrict__ wreg)
{
    const int q = blockIdx.x;
    const float* as = attnSum + (long)q * kN2;
    const float* sp = simS + (long)q * kN2;
    const float* rp = regS + (long)q * kN2;
    const int t = threadIdx.x;
    __shared__ float e[kN2];
    __shared__ float red[256];
    float mx = -1e30f;
    for (int i = t; i < kN2; i += 256) mx = fmaxf(mx, as[i]);
    red[t] = mx; __syncthreads();
    for (int s = 128; s > 0; s >>= 1) { if (t < s) red[t] = fmaxf(red[t], red[t + s]); __syncthreads(); }
    mx = red[0]; __syncthreads();
    float s1 = 0.f, s2 = 0.f;
    for (int i = t; i < kN2; i += 256) {
        const float ev = expf(as[i] - mx);
        e[i] = ev;
        const float m  = sp[i] > 0.75f ? 1.f : 0.f;
        const float mo = rp[i] > 0.99f ? 1.f : 0.f;
        s1 += ev * m;
        s2 += ev * m * mo;
    }
    red[t] = s1; __syncthreads();
    for (int s = 128; s > 0; s >>= 1) { if (t < s) red[t] += red[t + s]; __syncthreads(); }
    s1 = red[0]; __syncthreads();
    red[t] = s2; __syncthreads();
    for (int s = 128; s > 0; s >>= 1) { if (t < s) red[t] += red[t + s]; __syncthreads(); }
    s2 = red[0]; __syncthreads();
    const float i1 = 1.f / s1, i2 = 1.f / s2;
    for (int i = t; i < kN2; i += 256) {
        const float m  = sp[i] > 0.75f ? 1.f : 0.f;
        const float mo = rp[i] > 0.99f ? 1.f : 0.f;
        const float ev = e[i];
        wcls[(long)q * kN2 + i] = (_Float16)(ev * m * i1);
        wreg[(long)q * kN2 + i] = (_Float16)(ev * m * mo * i2);
    }
}

extern "C" void kernel_launch(void* const* d_in, const int* in_sizes, int n_in,
                              void* d_out, int out_size, void* d_ws, size_t ws_size,
                              hipStream_t stream)
{
    const float* x_cls     = (const float*)d_in[0];
    const float* x_reg     = (const float*)d_in[1];
    const float* cls_score = (const float*)d_in[2];
    const float* W_q_cls   = (const float*)d_in[4];
    const float* W_kv_cls  = (const float*)d_in[5];
    const float* W_q_reg   = (const float*)d_in[6];
    const float* W_kv_reg  = (const float*)d_in[7];
    const float* W_lin     = (const float*)d_in[8];
    const float* b_lin     = (const float*)d_in[9];
    const float* W_lin_reg = (const float*)d_in[10];
    const float* b_lin_reg = (const float*)d_in[11];
    float* out = (float*)d_out;

    if (ws_size < (size_t)128 * 1048576) return;

    // Workspace overlay (MiB offsets); peak use 122 MiB. Lifetimes commented.
    char* W = (char*)d_ws;
    auto at = [&](size_t mb) { return (void*)(W + mb * 1048576); };
    _Float16* WlinT_c = (_Float16*)at(0);    // [2048x2048] ph1->8
    _Float16* WlinT_r = (_Float16*)at(8);
    _Float16* kvh_c   = (_Float16*)at(16);   // [2048x2048] ph2->7
    _Float16* kvh_r   = (_Float16*)at(24);
    _Float16* vT_c    = (_Float16*)at(32);   // [1024x2048] ph3->9
    _Float16* vT_r    = (_Float16*)at(36);
    _Float16* qh_c    = (_Float16*)at(40);   // [512x1024]  ph2->3
    _Float16* qh_r    = (_Float16*)at(41);
    float*    attnS   = (float*)at(42);      // [512x2048]  ph6->9
    _Float16* xbf_c   = (_Float16*)at(46);   // [2048x1024] ph1->2
    _Float16* xbf_r   = (_Float16*)at(50);
    _Float16* WqT_c   = (_Float16*)at(54);   // [1024x1024] ph1->2
    _Float16* WqT_r   = (_Float16*)at(56);
    _Float16* WkvT_c  = (_Float16*)at(58);   // [2048x1024] ph1->2
    _Float16* WkvT_r  = (_Float16*)at(62);
    // overlays (dead regions reused):
    _Float16* qn_c    = (_Float16*)at(46);   // ph3->5
    _Float16* qn_r    = (_Float16*)at(47);
    _Float16* kn_c    = (_Float16*)at(48);   // ph3->5
    _Float16* kn_r    = (_Float16*)at(52);
    _Float16* vn_c    = (_Float16*)at(56);   // ph3->4
    _Float16* vn_r    = (_Float16*)at(60);
    _Float16* attn_h  = (_Float16*)at(46);   // [8x512x2048] ph6->7
    _Float16* xcat_c  = (_Float16*)at(62);   // [512x2048]  ph7->8
    _Float16* xcat_r  = (_Float16*)at(64);
    float*    simS    = (float*)at(66);      // ph4->9
    float*    regS    = (float*)at(70);
    float*    S       = (float*)at(74);      // [8x512x2048] f32, ph5->6
    _Float16* p_reg   = (_Float16*)at(106);  // [8x512x2048] ph5->6
    _Float16* w_c     = (_Float16*)at(74);   // ph9 (S dead)
    _Float16* w_r     = (_Float16*)at(76);

    const long sS = (long)kN1 * kN2;         // 1048576
    const long sVT = (long)kHD * kN2;        // 262144

    // Phase 1: casts + weight transposes
    cast_f2h<<<2048, 256, 0, stream>>>(x_cls, xbf_c, 524288);
    cast_f2h<<<2048, 256, 0, stream>>>(x_reg, xbf_r, 524288);
    transpose_h<float><<<dim3(32, 32), 256, 0, stream>>>(W_q_cls, kC, WqT_c, kC);
    transpose_h<float><<<dim3(32, 32), 256, 0, stream>>>(W_q_reg, kC, WqT_r, kC);
    transpose_h<float><<<dim3(64, 32), 256, 0, stream>>>(W_kv_cls, kC2, WkvT_c, kC);
    transpose_h<float><<<dim3(64, 32), 256, 0, stream>>>(W_kv_reg, kC2, WkvT_r, kC);
    transpose_h<float><<<dim3(64, 64), 256, 0, stream>>>(W_lin, kC2, WlinT_c, kC2);
    transpose_h<float><<<dim3(64, 64), 256, 0, stream>>>(W_lin_reg, kC2, WlinT_r, kC2);

    // Phase 2: projections (fp16 out)
    hgemm(stream, kN1, kC,  kC, xbf_c, kC, 0, WqT_c,  kC, 0, qh_c,  kC,  0, 1, 1.f, nullptr, nullptr, true);
    hgemm(stream, kN1, kC,  kC, xbf_r, kC, 0, WqT_r,  kC, 0, qh_r,  kC,  0, 1, 1.f, nullptr, nullptr, true);
    hgemm(stream, kN2, kC2, kC, xbf_c, kC, 0, WkvT_c, kC, 0, kvh_c, kC2, 0, 1, 1.f, nullptr, nullptr, true);
    hgemm(stream, kN2, kC2, kC, xbf_r, kC, 0, WkvT_r, kC, 0, kvh_r, kC2, 0, 1, 1.f, nullptr, nullptr, true);

    // Phase 3: norms + V transpose
    headnorm<<<kN1 * kH, 128, 0, stream>>>(qh_c,  kC,  0,  qn_c, kC, 0);
    headnorm<<<kN1 * kH, 128, 0, stream>>>(qh_r,  kC,  0,  qn_r, kC, 0);
    headnorm<<<kN2 * kH, 128, 0, stream>>>(kvh_c, kC2, 0,  kn_c, kC, 0);
    headnorm<<<kN2 * kH, 128, 0, stream>>>(kvh_r, kC2, 0,  kn_r, kC, 0);
    headnorm<<<kN2 * kH, 128, 0, stream>>>(kvh_c, kC2, kC, vn_c, kC, 0);
    headnorm<<<kN2 * kH, 128, 0, stream>>>(kvh_r, kC2, kC, vn_r, kC, 0);
    transpose_h<_Float16><<<dim3(32, 64), 256, 0, stream>>>(kvh_c + kC, kC2, vT_c, kN2);
    transpose_h<_Float16><<<dim3(32, 64), 256, 0, stream>>>(kvh_r + kC, kC2, vT_r, kN2);

    // Phase 4: v-v similarity (sum over heads / 8)
    hgemm(stream, kN1, kN2, kC, vn_c, kC, 0, vn_c, kC, 0, simS, kN2, 0, 1, 0.125f, nullptr, nullptr, false);
    hgemm(stream, kN1, kN2, kC, vn_r, kC, 0, vn_r, kC, 0, regS, kN2, 0, 1, 0.125f, nullptr, nullptr, false);

    // Phase 5: scores + softmax (reg first -> fp16 copy, then cls in place)
    hgemm(stream, kN1, kN2, kHD, qn_r, kC, kHD, kn_r, kC, kHD, S, kN2, sS, kH, 25.f, nullptr, nullptr, false);
    softmax_rows<<<kH * kN1, 256, 0, stream>>>(S);
    cast_f2h<<<8192, 256, 0, stream>>>(S, p_reg, 2097152);
    hgemm(stream, kN1, kN2, kHD, qn_c, kC, kHD, kn_c, kC, kHD, S, kN2, sS, kH, 25.f, cls_score, nullptr, false);
    softmax_rows<<<kH * kN1, 256, 0, stream>>>(S);

    // Phase 6: blend + head-mean
    blend_kernel<<<(kN1 * kN2) / 256, 256, 0, stream>>>(S, p_reg, attn_h, attnS);

    // Phase 7: attn @ V (per head) + x_ori concat
    hgemm(stream, kN1, kHD, kN2, attn_h, kN2, sS, vT_c, kN2, sVT, xcat_c, kC2, kHD, kH, 1.f, nullptr, nullptr, true);
    hgemm(stream, kN1, kHD, kN2, attn_h, kN2, sS, vT_r, kN2, sVT, xcat_r, kC2, kHD, kH, 1.f, nullptr, nullptr, true);
    copy_xori<<<(kN1 * kC) / 256, 256, 0, stream>>>(kvh_c, xcat_c);
    copy_xori<<<(kN1 * kC) / 256, 256, 0, stream>>>(kvh_r, xcat_r);

    // Phase 8: output linears -> out cols [1024,3072)
    hgemm(stream, kN1, kC2, kC2, xcat_c, kC2, 0, WlinT_c, kC2, 0, out + kC, kC3, 0, 1, 1.f, nullptr, b_lin, false);
    hgemm(stream, kN1, kC2, kC2, xcat_r, kC2, 0, WlinT_r, kC2, 0, out + (long)kN1 * kC3 + kC, kC3, 0, 1, 1.f, nullptr, b_lin_reg, false);

    // Phase 9: round-2 weights + ave features -> out cols [0,1024)
    round2_kernel<<<kN1, 256, 0, stream>>>(attnS, simS, regS, w_c, w_r);
    hgemm(stream, kN1, kHD, kN2, w_c, kN2, 0, vT_c, kN2, sVT, out, kC3, kHD, kH, 1.f, nullptr, nullptr, false);
    hgemm(stream, kN1, kHD, kN2, w_r, kN2, 0, vT_r, kN2, sVT, out + (long)kN1 * kC3, kC3, kHD, kH, 1.f, nullptr, nullptr, false);
}

// Round 3
// 507.624 us; speedup vs baseline: 3.0818x; 1.7461x over previous
//
#include <hip/hip_runtime.h>

// Problem constants (B=1)
constexpr int kN1 = 512;    // queries / local preds
constexpr int kN2 = 2048;   // keys
constexpr int kC  = 1024;   // channels
constexpr int kH  = 8;      // heads
constexpr int kHD = 128;    // head dim
constexpr int kC2 = 2048;   // 2C
constexpr int kC3 = 3072;   // 3C

typedef _Float16 half8 __attribute__((ext_vector_type(8)));
typedef _Float16 half4v __attribute__((ext_vector_type(4)));
typedef float f32x4 __attribute__((ext_vector_type(4)));

// async global->LDS, 16 B per lane; LDS dest is wave-uniform base + lane*16
#define GLD16(gptr, lptr) \
    __builtin_amdgcn_global_load_lds((const __attribute__((address_space(1))) void*)(gptr), \
                                     (__attribute__((address_space(3))) void*)(lptr), 16, 0, 0)

// ---------------------------------------------------------------------------
// fp16 NT MFMA GEMM with z-batching and split-K.
//   OUTK: 0 = fp32 store, 1 = fp16 store, 2 = fp32 unsafeAtomicAdd (split-K;
//         destination must be pre-zeroed; bias applied only by s==0 splits)
//   ZMODE: 0 = plain z (A,B,C strides linear in zz)
//          1 = head-merge: h=zz&7, g=zz>>3; Aoff=h*sAz, Boff=zz*sBz,
//              Coff=g*sCz2 + h*sCz   (attn@V: 16 virtual z over cls|reg)
// grid.z = Z * SK; zz = bz/SK, s = bz%SK, K range [s*K/SK,(s+1)*K/SK).
// Tile 128x128, BK=32, 256 threads. Requires M,N mult of 128 (N mult 128 per
// tile; grid.x covers N), K/SK mult of 32, lda/ldb mult of 8.
// ---------------------------------------------------------------------------
template<int OUTK, int COLSCALE, int BIAS, int ZMODE>
__global__ __launch_bounds__(256)
void hgemm_nt(int K, int SK,
              const _Float16* __restrict__ A, int lda, long sAz,
              const _Float16* __restrict__ B, int ldb, long sBz,
              void* __restrict__ Cv, int ldc, long sCz, long sCz2,
              float alpha,
              const float* __restrict__ colScale,
              const float* __restrict__ bias, long biasZ)
{
    __shared__ uint4 smem[1024];              // 16 KB: A tile 8 KB | B tile 8 KB
    char* ldsA = (char*)smem;
    char* ldsB = ldsA + 8192;
    const int tid = threadIdx.x;
    const int w = tid >> 6, l = tid & 63;
    const int m0 = blockIdx.y << 7, n0 = blockIdx.x << 7;
    const int wm = (w >> 1) << 6, wn = (w & 1) << 6;
    const int kq = l >> 4, lm = l & 15;

    const int bz = blockIdx.z;
    const int zz = bz / SK, s = bz - zz * SK;
    long Coff;
    if (ZMODE == 1) {
        const int h = zz & 7, g = zz >> 3;
        A += (long)h * sAz;
        B += (long)zz * sBz;
        Coff = (long)g * sCz2 + (long)h * sCz;
    } else {
        A += (long)zz * sAz;
        B += (long)zz * sBz;
        Coff = (long)zz * sCz;
    }
    const int kper = K / SK, kbeg = s * kper, kend = kbeg + kper;

    // staging: wave w stages chunks w and w+4 (chunk = 64 rows x one 8-elem kq)
    const int skq = w >> 1;               // kq of chunk w; chunk w+4 -> skq+2
    const int sr0 = (w & 1) << 6;         // row base 0 / 64
    const _Float16* gA = A + (long)(m0 + sr0 + l) * lda + skq * 8;
    const _Float16* gB = B + (long)(n0 + sr0 + l) * ldb + skq * 8;
    char* lA0 = ldsA + skq * 2048 + sr0 * 16 + l * 16;
    char* lB0 = ldsB + skq * 2048 + sr0 * 16 + l * 16;

    f32x4 acc[4][4] = {};

    for (int k0 = kbeg; k0 < kend; k0 += 32) {
        __syncthreads();                  // protect LDS from prior-iter readers
        GLD16(gA + k0,      lA0);
        GLD16(gA + k0 + 16, lA0 + 4096);
        GLD16(gB + k0,      lB0);
        GLD16(gB + k0 + 16, lB0 + 4096);
        __syncthreads();                  // drains vmcnt before reads
        half8 af[4], bfr[4];
        const char* pa = ldsA + kq * 2048 + (wm + lm) * 16;
        const char* pb = ldsB + kq * 2048 + (wn + lm) * 16;
        #pragma unroll
        for (int i = 0; i < 4; ++i) {
            af[i]  = *(const half8*)(pa + i * 256);
            bfr[i] = *(const half8*)(pb + i * 256);
        }
        #pragma unroll
        for (int mi = 0; mi < 4; ++mi)
            #pragma unroll
            for (int ni = 0; ni < 4; ++ni)
                acc[mi][ni] = __builtin_amdgcn_mfma_f32_16x16x32_f16(af[mi], bfr[ni], acc[mi][ni], 0, 0, 0);
    }

    // C/D layout: col = lane&15, row = (lane>>4)*4 + reg  [verified m89/m91]
    const int rbase = m0 + wm + kq * 4;
    const float* bz_bias = BIAS ? bias + zz * biasZ : nullptr;
    #pragma unroll
    for (int mi = 0; mi < 4; ++mi) {
        #pragma unroll
        for (int ni = 0; ni < 4; ++ni) {
            const int col = n0 + wn + ni * 16 + lm;
            const float cs = COLSCALE ? colScale[col] : 1.f;
            const float bs = BIAS ? bz_bias[col] : 0.f;
            #pragma unroll
            for (int r = 0; r < 4; ++r) {
                const long row = rbase + mi * 16 + r;
                float v = acc[mi][ni][r] * alpha;
                if (COLSCALE) v *= cs;
                if (BIAS && (OUTK != 2 || s == 0)) v += bs;
                const long off = Coff + row * ldc + col;
                if (OUTK == 0)      ((float*)Cv)[off] = v;
                else if (OUTK == 1) ((_Float16*)Cv)[off] = (_Float16)v;
                else                unsafeAtomicAdd(&((float*)Cv)[off], v);
            }
        }
    }
}

// ---------------------------------------------------------------------------
// fp32 -> fp16 elementwise cast, 4 elems/thread
// ---------------------------------------------------------------------------
__global__ __launch_bounds__(256)
void cast_f2h(const float* __restrict__ s, _Float16* __restrict__ d, int n4)
{
    const int i = blockIdx.x * 256 + threadIdx.x;
    if (i < n4) {
        const float4 v = ((const float4*)s)[i];
        half4v o;
        o.x = (_Float16)v.x; o.y = (_Float16)v.y; o.z = (_Float16)v.z; o.w = (_Float16)v.w;
        ((half4v*)d)[i] = o;
    }
}

// ---------------------------------------------------------------------------
// Transpose-cast to fp16: dst[n][k] = src[k][n]. Grid (Ncols/32, Krows/32).
// ---------------------------------------------------------------------------
template<typename T>
__global__ __launch_bounds__(256)
void transpose_h(const T* __restrict__ src, int ldsrc, _Float16* __restrict__ dst, int lddst)
{
    __shared__ float t[32][33];
    const int n0 = blockIdx.x << 5, k0 = blockIdx.y << 5;
    const int tx = threadIdx.x & 31, ty = threadIdx.x >> 5;
    #pragma unroll
    for (int j = ty; j < 32; j += 8)
        t[j][tx] = (float)src[(size_t)(k0 + j) * ldsrc + n0 + tx];
    __syncthreads();
    #pragma unroll
    for (int j = ty; j < 32; j += 8)
        dst[(size_t)(n0 + j) * lddst + k0 + tx] = (_Float16)t[tx][j];
}

// ---------------------------------------------------------------------------
// Per-(row,head) L2 norm over 128 elems; handles cls (b<nrh) and reg halves.
// ---------------------------------------------------------------------------
template<typename T>
__global__ __launch_bounds__(128)
void headnorm(const T* __restrict__ src_c, const T* __restrict__ src_r, int ls, int so,
              _Float16* __restrict__ dst_c, _Float16* __restrict__ dst_r, int ld, int nrh)
{
    int b = blockIdx.x;
    const T* src = src_c;
    _Float16* dst = dst_c;
    if (b >= nrh) { b -= nrh; src = src_r; dst = dst_r; }
    const int row = b >> 3, h = b & 7, t = threadIdx.x;
    const float v = (float)src[(size_t)row * ls + so + h * kHD + t];
    __shared__ float red[128];
    red[t] = v * v; __syncthreads();
    for (int s = 64; s > 0; s >>= 1) { if (t < s) red[t] += red[t + s]; __syncthreads(); }
    dst[(size_t)row * ld + h * kHD + t] = (_Float16)(v * rsqrtf(red[0]));
}

// ---------------------------------------------------------------------------
// Row softmax over 2048 cols, fp32 in place.
// ---------------------------------------------------------------------------
__global__ __launch_bounds__(256)
void softmax_rows(float* __restrict__ S)
{
    float* p = S + (long)blockIdx.x * kN2;
    const int t = threadIdx.x;
    __shared__ float red[256];
    float mx = -1e30f;
    for (int i = t; i < kN2; i += 256) mx = fmaxf(mx, p[i]);
    red[t] = mx; __syncthreads();
    for (int s = 128; s > 0; s >>= 1) { if (t < s) red[t] = fmaxf(red[t], red[t + s]); __syncthreads(); }
    mx = red[0]; __syncthreads();
    float sum = 0.f;
    for (int i = t; i < kN2; i += 256) { float e = expf(p[i] - mx); p[i] = e; sum += e; }
    red[t] = sum; __syncthreads();
    for (int s = 128; s > 0; s >>= 1) { if (t < s) red[t] += red[t + s]; __syncthreads(); }
    const float inv = 1.f / red[0];
    for (int i = t; i < kN2; i += 256) p[i] *= inv;
}

// ---------------------------------------------------------------------------
// attn = (S_cls + P_reg)/2 -> fp16 attn; attnS = mean over heads (fp32)
// ---------------------------------------------------------------------------
__global__ __launch_bounds__(256)
void blend_kernel(const float* __restrict__ Scls, const _Float16* __restrict__ Preg,
                  _Float16* __restrict__ attn, float* __restrict__ attnS)
{
    const long idx = (long)blockIdx.x * 256 + threadIdx.x;   // over N1*N2
    const int q = (int)(idx >> 11), k = (int)(idx & 2047);
    float s = 0.f;
    #pragma unroll
    for (int h = 0; h < kH; ++h) {
        const long o = ((long)h * kN1 + q) * kN2 + k;
        const float a = 0.5f * (Scls[o] + (float)Preg[o]);
        attn[o] = (_Float16)a;
        s += a;
    }
    attnS[idx] = s * 0.125f;
}

// ---------------------------------------------------------------------------
// Build xcat16 [2][512][2048]: cols<1024 cast from xcat32 [2][512][1024],
// cols>=1024 from kvh V-half rows 0..511 (kvh_c|kvh_r contiguous).
// ---------------------------------------------------------------------------
__global__ __launch_bounds__(256)
void build_xcat(const float* __restrict__ xc32, const _Float16* __restrict__ kvh,
                _Float16* __restrict__ xcat)
{
    const int idx = blockIdx.x * 256 + threadIdx.x;   // 2*512*2048
    const int j = idx & 2047;
    const int n = (idx >> 11) & 511;
    const int g = idx >> 20;
    _Float16 v;
    if (j < 1024) v = (_Float16)xc32[(g << 19) + (n << 10) + j];
    else          v = kvh[(long)g * 4194304 + (long)n * 2048 + j];
    xcat[idx] = v;
}

// ---------------------------------------------------------------------------
// Round-2 masked renormalized weights (softmax denom cancels), fp16 out.
// ---------------------------------------------------------------------------
__global__ __launch_bounds__(256)
void round2_kernel(const float* __restrict__ attnSum,
                   const float* __restrict__ simS, const float* __restrict__ regS,
                   _Float16* __restrict__ wcls, _Float16* __restrict__ wreg)
{
    const int q = blockIdx.x;
    const float* as = attnSum + (long)q * kN2;
    const float* sp = simS + (long)q * kN2;
    const float* rp = regS + (long)q * kN2;
    const int t = threadIdx.x;
    __shared__ float e[kN2];
    __shared__ float red[256];
    float mx = -1e30f;
    for (int i = t; i < kN2; i += 256) mx = fmaxf(mx, as[i]);
    red[t] = mx; __syncthreads();
    for (int s = 128; s > 0; s >>= 1) { if (t < s) red[t] = fmaxf(red[t], red[t + s]); __syncthreads(); }
    mx = red[0]; __syncthreads();
    float s1 = 0.f, s2 = 0.f;
    for (int i = t; i < kN2; i += 256) {
        const float ev = expf(as[i] - mx);
        e[i] = ev;
        const float m  = sp[i] > 0.75f ? 1.f : 0.f;
        const float mo = rp[i] > 0.99f ? 1.f : 0.f;
        s1 += ev * m;
        s2 += ev * m * mo;
    }
    red[t] = s1; __syncthreads();
    for (int s = 128; s > 0; s >>= 1) { if (t < s) red[t] += red[t + s]; __syncthreads(); }
    s1 = red[0]; __syncthreads();
    red[t] = s2; __syncthreads();
    for (int s = 128; s > 0; s >>= 1) { if (t < s) red[t] += red[t + s]; __syncthreads(); }
    s2 = red[0]; __syncthreads();
    const float i1 = 1.f / s1, i2 = 1.f / s2;
    for (int i = t; i < kN2; i += 256) {
        const float m  = sp[i] > 0.75f ? 1.f : 0.f;
        const float mo = rp[i] > 0.99f ? 1.f : 0.f;
        const float ev = e[i];
        wcls[(long)q * kN2 + i] = (_Float16)(ev * m * i1);
        wreg[(long)q * kN2 + i] = (_Float16)(ev * m * mo * i2);
    }
}

extern "C" void kernel_launch(void* const* d_in, const int* in_sizes, int n_in,
                              void* d_out, int out_size, void* d_ws, size_t ws_size,
                              hipStream_t stream)
{
    const float* x_cls     = (const float*)d_in[0];
    const float* x_reg     = (const float*)d_in[1];
    const float* cls_score = (const float*)d_in[2];
    const float* W_q_cls   = (const float*)d_in[4];
    const float* W_kv_cls  = (const float*)d_in[5];
    const float* W_q_reg   = (const float*)d_in[6];
    const float* W_kv_reg  = (const float*)d_in[7];
    const float* W_lin     = (const float*)d_in[8];
    const float* b_lin     = (const float*)d_in[9];
    const float* W_lin_reg = (const float*)d_in[10];
    const float* b_lin_reg = (const float*)d_in[11];
    float* out = (float*)d_out;

    if (ws_size < (size_t)128 * 1048576) return;

    // Workspace overlay (MiB offsets); peak 127 MiB. Phase lifetimes noted.
    char* W = (char*)d_ws;
    auto at = [&](size_t mb) { return (void*)(W + mb * 1048576); };
    _Float16* WlinT   = (_Float16*)at(0);    // [2][2048x2048] ph1->8
    _Float16* kvh     = (_Float16*)at(16);   // [2][2048x2048] ph2->7 (K|V halves)
    _Float16* vT      = (_Float16*)at(32);   // [2][1024x2048] ph3->9
    float*    qh32    = (float*)at(40);      // [2][512x1024]  ph2->3 (split-K acc)
    float*    biasWS  = (float*)at(44);      // [2][2048]      ph1->8
    float*    attnS   = (float*)at(45);      // [512x2048]     ph6->9
    _Float16* xbf     = (_Float16*)at(49);   // [2][2048x1024] ph1->2
    _Float16* WqT     = (_Float16*)at(57);   // [2][1024x1024] ph1->2
    _Float16* WkvT    = (_Float16*)at(61);   // [2][2048x1024] ph1->2
    _Float16* p_reg   = (_Float16*)at(49);   // [8x512x2048]   ph5->6 (over xbf/WqT/WkvT)
    _Float16* qn      = (_Float16*)at(69);   // [2][512x1024]  ph3->5
    _Float16* kn      = (_Float16*)at(71);   // [2][2048x1024] ph3->5
    _Float16* vn      = (_Float16*)at(79);   // [2][2048x1024] ph3->4
    _Float16* attn_h  = (_Float16*)at(69);   // [8x512x2048]   ph6->7 (over qn/kn/vn)
    float*    simS    = (float*)at(87);      // [512x2048]     ph4->9
    float*    regS    = (float*)at(91);      // [512x2048]     ph4->9
    float*    S       = (float*)at(95);      // [8x512x2048] f32 ph5->6
    float*    xcat32  = (float*)at(95);      // [2][512x1024]  ph7 (S dead)
    _Float16* xcat16  = (_Float16*)at(99);   // [2][512x2048]  ph7->8
    _Float16* w_c     = (_Float16*)at(103);  // [512x2048]     ph9
    _Float16* w_r     = (_Float16*)at(105);

    // Zero split-K accumulators and d_out (ave/out-lin atomically add into it)
    hipMemsetAsync(d_out, 0, (size_t)out_size * 4, stream);
    hipMemsetAsync(qh32, 0, (size_t)4 * 1048576, stream);
    hipMemsetAsync(simS, 0, (size_t)8 * 1048576, stream);   // simS+regS
    hipMemsetAsync(xcat32, 0, (size_t)4 * 1048576, stream);
    hipMemcpyAsync(biasWS,        b_lin,     kC2 * 4, hipMemcpyDeviceToDevice, stream);
    hipMemcpyAsync(biasWS + kC2,  b_lin_reg, kC2 * 4, hipMemcpyDeviceToDevice, stream);

    // Phase 1: casts + weight transposes
    cast_f2h<<<2048, 256, 0, stream>>>(x_cls, xbf,           524288);
    cast_f2h<<<2048, 256, 0, stream>>>(x_reg, xbf + 2097152, 524288);
    transpose_h<float><<<dim3(32, 32), 256, 0, stream>>>(W_q_cls,  kC,  WqT,            kC);
    transpose_h<float><<<dim3(32, 32), 256, 0, stream>>>(W_q_reg,  kC,  WqT + 1048576,  kC);
    transpose_h<float><<<dim3(64, 32), 256, 0, stream>>>(W_kv_cls, kC2, WkvT,           kC);
    transpose_h<float><<<dim3(64, 32), 256, 0, stream>>>(W_kv_reg, kC2, WkvT + 2097152, kC);
    transpose_h<float><<<dim3(64, 64), 256, 0, stream>>>(W_lin,     kC2, WlinT,           kC2);
    transpose_h<float><<<dim3(64, 64), 256, 0, stream>>>(W_lin_reg, kC2, WlinT + 4194304, kC2);

    // Phase 2: projections. q: z=2 merged, SK=4 -> fp32 atomic. kv: z=2, 512 blocks.
    hgemm_nt<2, 0, 0, 0><<<dim3(8, 4, 8), 256, 0, stream>>>(kC, 4,
        xbf, kC, 2097152, WqT, kC, 1048576, qh32, kC, 524288, 0, 1.f, nullptr, nullptr, 0);
    hgemm_nt<1, 0, 0, 0><<<dim3(16, 16, 2), 256, 0, stream>>>(kC, 1,
        xbf, kC, 2097152, WkvT, kC, 2097152, kvh, kC2, 4194304, 0, 1.f, nullptr, nullptr, 0);

    // Phase 3: norms (cls+reg merged per launch) + V transposes
    headnorm<float><<<2 * kN1 * kH, 128, 0, stream>>>(qh32, qh32 + 524288, kC, 0,
        qn, qn + 524288, kC, kN1 * kH);
    headnorm<_Float16><<<2 * kN2 * kH, 128, 0, stream>>>(kvh, kvh + 4194304, kC2, 0,
        kn, kn + 2097152, kC, kN2 * kH);
    headnorm<_Float16><<<2 * kN2 * kH, 128, 0, stream>>>(kvh, kvh + 4194304, kC2, kC,
        vn, vn + 2097152, kC, kN2 * kH);
    transpose_h<_Float16><<<dim3(32, 64), 256, 0, stream>>>(kvh + kC,           kC2, vT,           kN2);
    transpose_h<_Float16><<<dim3(32, 64), 256, 0, stream>>>(kvh + 4194304 + kC, kC2, vT + 2097152, kN2);

    // Phase 4: v-v similarity (head-sum/8), z=2 merged, SK=2
    hgemm_nt<2, 0, 0, 0><<<dim3(16, 4, 4), 256, 0, stream>>>(kC, 2,
        vn, kC, 2097152, vn, kC, 2097152, simS, kN2, 1048576, 0, 0.125f, nullptr, nullptr, 0);

    // Phase 5: scores + softmax (reg -> fp16 copy, then cls reuses S)
    hgemm_nt<0, 0, 0, 0><<<dim3(16, 4, 8), 256, 0, stream>>>(kHD, 1,
        qn + 524288, kC, kHD, kn + 2097152, kC, kHD, S, kN2, 1048576, 0, 25.f, nullptr, nullptr, 0);
    softmax_rows<<<kH * kN1, 256, 0, stream>>>(S);
    cast_f2h<<<8192, 256, 0, stream>>>(S, p_reg, 2097152);
    hgemm_nt<0, 1, 0, 0><<<dim3(16, 4, 8), 256, 0, stream>>>(kHD, 1,
        qn, kC, kHD, kn, kC, kHD, S, kN2, 1048576, 0, 25.f, cls_score, nullptr, 0);
    softmax_rows<<<kH * kN1, 256, 0, stream>>>(S);

    // Phase 6: blend + head-mean
    blend_kernel<<<(kN1 * kN2) / 256, 256, 0, stream>>>(S, p_reg, attn_h, attnS);

    // Phase 7: attn @ V, 16 virtual z (8 heads x cls|reg) via ZMODE=1, SK=4
    hgemm_nt<2, 0, 0, 1><<<dim3(1, 4, 64), 256, 0, stream>>>(kN2, 4,
        attn_h, kN2, 1048576, vT, kN2, 262144, xcat32, kC, 128, 524288, 1.f, nullptr, nullptr, 0);
    build_xcat<<<8192, 256, 0, stream>>>(xcat32, kvh, xcat16);

    // Phase 8: output linears -> out cols [1024,3072), z=2 merged, SK=2, bias
    hgemm_nt<2, 0, 1, 0><<<dim3(16, 4, 4), 256, 0, stream>>>(kC2, 2,
        xcat16, kC2, 1048576, WlinT, kC2, 4194304, out + kC, kC3, (long)kN1 * kC3, 0,
        1.f, nullptr, biasWS, kC2);

    // Phase 9: round-2 weights + ave features -> out cols [0,1024), z=2, SK=4
    round2_kernel<<<kN1, 256, 0, stream>>>(attnS, simS, regS, w_c, w_r);
    hgemm_nt<2, 0, 0, 0><<<dim3(8, 4, 8), 256, 0, stream>>>(kN2, 4,
        w_c, kN2, 1048576, vT, kN2, 2097152, out, kC3, (long)kN1 * kC3, 0,
        1.f, nullptr, nullptr, 0);
}

// Round 4
// 455.956 us; speedup vs baseline: 3.4311x; 1.1133x over previous
//
#include <hip/hip_runtime.h>

// Problem constants (B=1)
constexpr int kN1 = 512;
constexpr int kN2 = 2048;
constexpr int kC  = 1024;
constexpr int kH  = 8;
constexpr int kHD = 128;
constexpr int kC2 = 2048;
constexpr int kC3 = 3072;

typedef _Float16 half8 __attribute__((ext_vector_type(8)));
typedef _Float16 half4v __attribute__((ext_vector_type(4)));
typedef float f32x4 __attribute__((ext_vector_type(4)));

// async global->LDS, 16 B per lane; LDS dest is wave-uniform base + lane*16
#define GLD16(gptr, lptr) \
    __builtin_amdgcn_global_load_lds((const __attribute__((address_space(1))) void*)(gptr), \
                                     (__attribute__((address_space(3))) void*)(lptr), 16, 0, 0)

// s_waitcnt immediates: vmcnt in [3:0]|[15:14], expcnt [6:4], lgkmcnt [11:8]
#define WAIT_VM4  0x0F74   // vmcnt(4), expcnt/lgkm ignored
#define WAIT_VM0  0x0F70   // vmcnt(0)
#define WAIT_LGKM0 0xC07F  // lgkmcnt(0), vmcnt/expcnt ignored

// ---------------------------------------------------------------------------
// fp16 NT MFMA GEMM, double-buffered (raw s_barrier + manual vmcnt),
// z-batching with (h,g) decomposition, split-K.
//   OUTK: 0 fp32 store, 1 fp16 store, 2 fp32 unsafeAtomicAdd (dest pre-zeroed,
//         bias only on s==0 splits)
//   zz = blockIdx.z / SK; h = zz & hmask; g = zz >> hshift.
//   offsets: A += h*sAz + g*sAz2 (same for B); Coff = h*sCz + g*sCz2.
//   OUTVT: additionally store transposed fp16 V-half (cols>=1024) to
//          vt[zz*vtSz + (col-1024)*2048 + row]  (kv-projection epilogue).
// Tile 128x128, BK=32, 256 threads, 32 KB LDS (2 buffers).
// ---------------------------------------------------------------------------
template<int OUTK, int COLSCALE, int BIAS, int OUTVT>
__global__ __launch_bounds__(256)
void hgemm_nt(int K, int SK,
              const _Float16* __restrict__ A, long sAz, long sAz2, int lda,
              const _Float16* __restrict__ B, long sBz, long sBz2, int ldb,
              void* __restrict__ Cv, long sCz, long sCz2, int ldc,
              int hmask, int hshift, float alpha,
              const float* __restrict__ colScale,
              const float* __restrict__ bias, long biasZ,
              _Float16* __restrict__ vt, long vtSz)
{
    __shared__ uint4 smem[2048];              // 32 KB: 2 x (A 8 KB | B 8 KB)
    char* smembase = (char*)smem;
    const int tid = threadIdx.x;
    const int w = tid >> 6, l = tid & 63;
    const int m0 = blockIdx.y << 7, n0 = blockIdx.x << 7;
    const int wm = (w >> 1) << 6, wn = (w & 1) << 6;
    const int kq = l >> 4, lm = l & 15;

    const int bz = blockIdx.z;
    const int zz = bz / SK, s = bz - zz * SK;
    const int h = zz & hmask, g = zz >> hshift;
    A += (long)h * sAz + (long)g * sAz2;
    B += (long)h * sBz + (long)g * sBz2;
    const long Coff = (long)h * sCz + (long)g * sCz2;
    const int kper = K / SK, kbeg = s * kper;
    const int nIter = kper >> 5;

    // staging: wave w stages chunks (skq) and (skq+2) for rows sr0..sr0+63
    const int skq = w >> 1;
    const int sr0 = (w & 1) << 6;
    const _Float16* gA = A + (long)(m0 + sr0 + l) * lda + skq * 8 + kbeg;
    const _Float16* gB = B + (long)(n0 + sr0 + l) * ldb + skq * 8 + kbeg;
    const int soff = skq * 2048 + (sr0 + l) * 16;

    auto stage = [&](int it, int b) {
        char* dst = smembase + b * 16384;
        const int k0 = it << 5;
        GLD16(gA + k0,      dst + soff);
        GLD16(gA + k0 + 16, dst + soff + 4096);
        GLD16(gB + k0,      dst + 8192 + soff);
        GLD16(gB + k0 + 16, dst + 8192 + soff + 4096);
    };

    f32x4 acc[4][4] = {};
    stage(0, 0);

    for (int it = 0; it < nIter; ++it) {
        const int cur = it & 1;
        const bool hasNext = (it + 1 < nIter);
        if (hasNext) stage(it + 1, cur ^ 1);
        if (hasNext) __builtin_amdgcn_s_waitcnt(WAIT_VM4);   // tile-it loads done
        else         __builtin_amdgcn_s_waitcnt(WAIT_VM0);
        __builtin_amdgcn_s_barrier();                        // all waves' loads done
        const char* cbase = smembase + cur * 16384;
        half8 af[4], bfr[4];
        const char* pa = cbase + kq * 2048 + (wm + lm) * 16;
        const char* pb = cbase + 8192 + kq * 2048 + (wn + lm) * 16;
        #pragma unroll
        for (int i = 0; i < 4; ++i) {
            af[i]  = *(const half8*)(pa + i * 256);
            bfr[i] = *(const half8*)(pb + i * 256);
        }
        #pragma unroll
        for (int mi = 0; mi < 4; ++mi)
            #pragma unroll
            for (int ni = 0; ni < 4; ++ni)
                acc[mi][ni] = __builtin_amdgcn_mfma_f32_16x16x32_f16(af[mi], bfr[ni], acc[mi][ni], 0, 0, 0);
        __builtin_amdgcn_s_waitcnt(WAIT_LGKM0);              // own ds_reads retired
        __builtin_amdgcn_s_barrier();                        // all done reading cur
    }

    // C/D layout: col = lane&15, row = (lane>>4)*4 + reg  [verified m89/m91]
    const int rbase = m0 + wm + kq * 4;
    const float* bz_bias = BIAS ? bias + zz * biasZ : nullptr;
    #pragma unroll
    for (int mi = 0; mi < 4; ++mi) {
        #pragma unroll
        for (int ni = 0; ni < 4; ++ni) {
            const int col = n0 + wn + ni * 16 + lm;
            const float cs = COLSCALE ? colScale[col] : 1.f;
            const float bs = BIAS ? bz_bias[col] : 0.f;
            #pragma unroll
            for (int r = 0; r < 4; ++r) {
                const long row = rbase + mi * 16 + r;
                float v = acc[mi][ni][r] * alpha;
                if (COLSCALE) v *= cs;
                if (BIAS && (OUTK != 2 || s == 0)) v += bs;
                const long off = Coff + row * ldc + col;
                if (OUTK == 0)      ((float*)Cv)[off] = v;
                else if (OUTK == 1) ((_Float16*)Cv)[off] = (_Float16)v;
                else                unsafeAtomicAdd(&((float*)Cv)[off], v);
                if (OUTVT && col >= 1024)
                    vt[(long)zz * vtSz + (long)(col - 1024) * 2048 + row] = (_Float16)v;
            }
        }
    }
}

// ---------------------------------------------------------------------------
// fp32 -> fp16 cast, z picks (x_cls | x_reg) -> xbf[z]
// ---------------------------------------------------------------------------
__global__ __launch_bounds__(256)
void cast_f2h(const float* __restrict__ s0, const float* __restrict__ s1,
              _Float16* __restrict__ d, int n4)
{
    const int i = blockIdx.x * 256 + threadIdx.x;
    const float* s = blockIdx.y ? s1 : s0;
    const float4 v = ((const float4*)s)[i];
    half4v o;
    o.x = (_Float16)v.x; o.y = (_Float16)v.y; o.z = (_Float16)v.z; o.w = (_Float16)v.w;
    ((half4v*)(d + (size_t)blockIdx.y * n4 * 4))[i] = o;
}

// ---------------------------------------------------------------------------
// Transpose-cast fp32->fp16: dst[z][n][k] = src_z[k][n]. Grid (N/32, K/32, 2).
// ---------------------------------------------------------------------------
__global__ __launch_bounds__(256)
void transpose_h(const float* __restrict__ s0, const float* __restrict__ s1, int ldsrc,
                 _Float16* __restrict__ dst, long dstZ, int lddst)
{
    __shared__ float t[32][33];
    const float* src = blockIdx.z ? s1 : s0;
    _Float16* d = dst + (long)blockIdx.z * dstZ;
    const int n0 = blockIdx.x << 5, k0 = blockIdx.y << 5;
    const int tx = threadIdx.x & 31, ty = threadIdx.x >> 5;
    #pragma unroll
    for (int j = ty; j < 32; j += 8)
        t[j][tx] = src[(size_t)(k0 + j) * ldsrc + n0 + tx];
    __syncthreads();
    #pragma unroll
    for (int j = ty; j < 32; j += 8)
        d[(size_t)(n0 + j) * lddst + k0 + tx] = (_Float16)t[tx][j];
}

// ---------------------------------------------------------------------------
// Wave-per-vector L2 norms (128-elem vectors, 2 elems/lane, shuffle reduce)
// ---------------------------------------------------------------------------
__global__ __launch_bounds__(256)
void headnorm_q(const float* __restrict__ qh32, _Float16* __restrict__ qn)
{
    const int vid = blockIdx.x * 4 + (threadIdx.x >> 6);   // [0, 8192)
    const int lane = threadIdx.x & 63;
    const int g = vid >> 12, rr = vid & 4095, row = rr >> 3, hh = rr & 7;
    const size_t o = (size_t)g * 524288 + (size_t)row * 1024 + hh * 128 + lane * 2;
    const float2 v = *(const float2*)(qh32 + o);
    float ss = v.x * v.x + v.y * v.y;
    #pragma unroll
    for (int d = 32; d > 0; d >>= 1) ss += __shfl_xor(ss, d, 64);
    const float inv = rsqrtf(ss);
    half4v dummy;
    _Float16* dp = qn + o;
    dp[0] = (_Float16)(v.x * inv); dp[1] = (_Float16)(v.y * inv);
    (void)dummy;
}

__global__ __launch_bounds__(256)
void headnorm_kv(const _Float16* __restrict__ kvh,
                 _Float16* __restrict__ kn, _Float16* __restrict__ vn)
{
    const int vid = blockIdx.x * 4 + (threadIdx.x >> 6);   // [0, 65536)
    const int lane = threadIdx.x & 63;
    const int half_ = vid >> 15;                // 0 = K, 1 = V
    const int r15 = vid & 32767;
    const int g = r15 >> 14, rr = r15 & 16383, row = rr >> 3, hh = rr & 7;
    const _Float16* sp = kvh + (size_t)g * 4194304 + (size_t)row * 2048
                             + half_ * 1024 + hh * 128 + lane * 2;
    const float a = (float)sp[0], b = (float)sp[1];
    float ss = a * a + b * b;
    #pragma unroll
    for (int d = 32; d > 0; d >>= 1) ss += __shfl_xor(ss, d, 64);
    const float inv = rsqrtf(ss);
    _Float16* dp = (half_ ? vn : kn) + (size_t)g * 2097152 + (size_t)row * 1024
                                     + hh * 128 + lane * 2;
    dp[0] = (_Float16)(a * inv); dp[1] = (_Float16)(b * inv);
}

// ---------------------------------------------------------------------------
// Block reduce (256 threads, 4 waves) via shfl + 4-slot LDS. OP: 0 sum, 1 max
// ---------------------------------------------------------------------------
template<int OP>
__device__ __forceinline__ float bred(float v, float* lds)
{
    #pragma unroll
    for (int o = 32; o > 0; o >>= 1) {
        const float u = __shfl_xor(v, o, 64);
        v = OP ? fmaxf(v, u) : v + u;
    }
    __syncthreads();
    if ((threadIdx.x & 63) == 0) lds[threadIdx.x >> 6] = v;
    __syncthreads();
    return OP ? fmaxf(fmaxf(lds[0], lds[1]), fmaxf(lds[2], lds[3]))
              : lds[0] + lds[1] + lds[2] + lds[3];
}

// ---------------------------------------------------------------------------
// Row softmax (2048 cols) + fp16 cast: P[row] = softmax(S[row])
// ---------------------------------------------------------------------------
__global__ __launch_bounds__(256)
void softmax_cast(const float* __restrict__ S, _Float16* __restrict__ P)
{
    __shared__ float lds[4];
    const size_t base = (size_t)blockIdx.x * 2048;
    const int t = threadIdx.x;
    float v[8];
    float mx = -1e30f;
    #pragma unroll
    for (int j = 0; j < 8; ++j) { v[j] = S[base + t + 256 * j]; mx = fmaxf(mx, v[j]); }
    mx = bred<1>(mx, lds);
    float sum = 0.f;
    #pragma unroll
    for (int j = 0; j < 8; ++j) { v[j] = expf(v[j] - mx); sum += v[j]; }
    sum = bred<0>(sum, lds);
    const float inv = 1.f / sum;
    #pragma unroll
    for (int j = 0; j < 8; ++j) P[base + t + 256 * j] = (_Float16)(v[j] * inv);
}

// ---------------------------------------------------------------------------
// Fused: cls softmax + blend with reg probs + head-mean + round-2 masked
// renormalized weights. One block per q row.
// ---------------------------------------------------------------------------
__global__ __launch_bounds__(256)
void sb_kernel(const float* __restrict__ S, const _Float16* __restrict__ Preg,
               const float* __restrict__ simS, const float* __restrict__ regS,
               _Float16* __restrict__ attn,
               _Float16* __restrict__ wc, _Float16* __restrict__ wr)
{
    __shared__ float lds[4];
    const int q = blockIdx.x, t = threadIdx.x;
    float asum[8] = {};
    for (int hh = 0; hh < 8; ++hh) {
        const size_t rb = (size_t)(hh * 512 + q) * 2048;
        float vc[8];
        float mx = -1e30f;
        #pragma unroll
        for (int j = 0; j < 8; ++j) { vc[j] = S[rb + t + 256 * j]; mx = fmaxf(mx, vc[j]); }
        mx = bred<1>(mx, lds);
        float sum = 0.f;
        #pragma unroll
        for (int j = 0; j < 8; ++j) { vc[j] = expf(vc[j] - mx); sum += vc[j]; }
        sum = bred<0>(sum, lds);
        const float inv = 1.f / sum;
        #pragma unroll
        for (int j = 0; j < 8; ++j) {
            const float a = 0.5f * (vc[j] * inv + (float)Preg[rb + t + 256 * j]);
            attn[rb + t + 256 * j] = (_Float16)a;
            asum[j] += a;
        }
    }
    float mx = -1e30f;
    #pragma unroll
    for (int j = 0; j < 8; ++j) { asum[j] *= 0.125f; mx = fmaxf(mx, asum[j]); }
    mx = bred<1>(mx, lds);
    float em[8], emo[8];
    float s1 = 0.f, s2 = 0.f;
    const size_t qb = (size_t)q * 2048;
    #pragma unroll
    for (int j = 0; j < 8; ++j) {
        const float e = expf(asum[j] - mx);
        const float m  = simS[qb + t + 256 * j] > 0.75f ? 1.f : 0.f;
        const float mo = regS[qb + t + 256 * j] > 0.99f ? 1.f : 0.f;
        em[j] = e * m; emo[j] = e * m * mo;
        s1 += em[j]; s2 += emo[j];
    }
    s1 = bred<0>(s1, lds);
    s2 = bred<0>(s2, lds);
    const float i1 = 1.f / s1, i2 = 1.f / s2;
    #pragma unroll
    for (int j = 0; j < 8; ++j) {
        wc[qb + t + 256 * j] = (_Float16)(em[j] * i1);
        wr[qb + t + 256 * j] = (_Float16)(emo[j] * i2);
    }
}

// ---------------------------------------------------------------------------
// Build xcat16 [2][512][2048]: cols<1024 from xcat32, cols>=1024 from kvh V.
// ---------------------------------------------------------------------------
__global__ __launch_bounds__(256)
void build_xcat(const float* __restrict__ xc32, const _Float16* __restrict__ kvh,
                _Float16* __restrict__ xcat)
{
    const int idx = blockIdx.x * 256 + threadIdx.x;   // 2*512*2048
    const int j = idx & 2047;
    const int n = (idx >> 11) & 511;
    const int g = idx >> 20;
    _Float16 v;
    if (j < 1024) v = (_Float16)xc32[(g << 19) + (n << 10) + j];
    else          v = kvh[(size_t)g * 4194304 + (size_t)n * 2048 + j];
    xcat[idx] = v;
}

extern "C" void kernel_launch(void* const* d_in, const int* in_sizes, int n_in,
                              void* d_out, int out_size, void* d_ws, size_t ws_size,
                              hipStream_t stream)
{
    const float* x_cls     = (const float*)d_in[0];
    const float* x_reg     = (const float*)d_in[1];
    const float* cls_score = (const float*)d_in[2];
    const float* W_q_cls   = (const float*)d_in[4];
    const float* W_kv_cls  = (const float*)d_in[5];
    const float* W_q_reg   = (const float*)d_in[6];
    const float* W_kv_reg  = (const float*)d_in[7];
    const float* W_lin     = (const float*)d_in[8];
    const float* b_lin     = (const float*)d_in[9];
    const float* W_lin_reg = (const float*)d_in[10];
    const float* b_lin_reg = (const float*)d_in[11];
    float* out = (float*)d_out;

    if (ws_size < (size_t)127 * 1048576) return;

    // Workspace overlay (MiB offsets), peak 127 MiB:
    char* W = (char*)d_ws;
    auto at = [&](size_t mb) { return (void*)(W + mb * 1048576); };
    _Float16* WlinT  = (_Float16*)at(0);    // [2][2048x2048] ph1->outlin
    _Float16* kvh    = (_Float16*)at(16);   // [2][2048x2048] ph2->build_xcat
    _Float16* vT     = (_Float16*)at(32);   // [2][1024x2048] ph2->ave (raw V^T)
    float*    qh32   = (float*)at(40);      // [2][512x1024]  ph2->norm
    float*    xcat32 = (float*)at(40);      //   reuse after norm (attn@V acc)
    float*    biasWS = (float*)at(44);      // [2][2048]
    _Float16* xbf    = (_Float16*)at(45);   // [2][2048x1024] ph1->proj
    _Float16* p_reg  = (_Float16*)at(45);   // [8x512x2048]   reuse (45..61)
    _Float16* WqT    = (_Float16*)at(53);   // [2][1024x1024] ph1->proj
    _Float16* WkvT   = (_Float16*)at(57);   // [2][2048x1024] ph1->proj
    _Float16* qn     = (_Float16*)at(65);   // [2][512x1024]
    _Float16* kn     = (_Float16*)at(67);   // [2][2048x1024] ->scores
    _Float16* attn_h = (_Float16*)at(67);   // [8x512x2048]   reuse (67..83)
    _Float16* vn     = (_Float16*)at(75);   // [2][2048x1024] ->v-sim
    float*    simS   = (float*)at(83);      // [512x2048]
    float*    regS   = (float*)at(87);      // [512x2048]
    float*    S      = (float*)at(91);      // [8x512x2048] fp32 raw scores
    _Float16* w_c    = (_Float16*)at(123);  // [512x2048]
    _Float16* w_r    = (_Float16*)at(125);
    _Float16* xcat16 = (_Float16*)at(16);   // placeholder (reassigned below)
    // xcat16 needs 8 MB live build_xcat->out-lin; S region is dead by then:
    xcat16 = (_Float16*)at(91);

    const long NONE = 0;

    hipMemsetAsync(d_out, 0, (size_t)out_size * 4, stream);
    hipMemsetAsync(qh32, 0, (size_t)4 * 1048576, stream);
    hipMemsetAsync(simS, 0, (size_t)8 * 1048576, stream);   // simS+regS
    hipMemcpyAsync(biasWS,       b_lin,     kC2 * 4, hipMemcpyDeviceToDevice, stream);
    hipMemcpyAsync(biasWS + kC2, b_lin_reg, kC2 * 4, hipMemcpyDeviceToDevice, stream);

    // Phase 1: prep (4 launches)
    cast_f2h<<<dim3(2048, 2), 256, 0, stream>>>(x_cls, x_reg, xbf, 524288);
    transpose_h<<<dim3(32, 32, 2), 256, 0, stream>>>(W_q_cls, W_q_reg, kC, WqT, 1048576, kC);
    transpose_h<<<dim3(64, 32, 2), 256, 0, stream>>>(W_kv_cls, W_kv_reg, kC2, WkvT, 2097152, kC);
    transpose_h<<<dim3(64, 64, 2), 256, 0, stream>>>(W_lin, W_lin_reg, kC2, WlinT, 4194304, kC2);

    // Phase 2: projections. q: SK=8 atomic; kv: SK=1 fp16 + fused V^T epilogue
    hgemm_nt<2, 0, 0, 0><<<dim3(8, 4, 16), 256, 0, stream>>>(kC, 8,
        xbf, 2097152, NONE, kC, WqT, 1048576, NONE, kC,
        qh32, 524288, NONE, kC, 63, 6, 1.f, nullptr, nullptr, 0, nullptr, 0);
    hgemm_nt<1, 0, 0, 1><<<dim3(16, 16, 2), 256, 0, stream>>>(kC, 1,
        xbf, 2097152, NONE, kC, WkvT, 2097152, NONE, kC,
        kvh, 4194304, NONE, kC2, 63, 6, 1.f, nullptr, nullptr, 0, vT, 2097152);

    // Phase 3: norms (wave per 128-vector)
    headnorm_q<<<2048, 256, 0, stream>>>(qh32, qn);
    headnorm_kv<<<16384, 256, 0, stream>>>(kvh, kn, vn);
    hipMemsetAsync(xcat32, 0, (size_t)4 * 1048576, stream);  // qh32 region now free

    // Phase 4: v-v similarity (head-sum/8), z=2, SK=4
    hgemm_nt<2, 0, 0, 0><<<dim3(16, 4, 8), 256, 0, stream>>>(kC, 4,
        vn, 2097152, NONE, kC, vn, 2097152, NONE, kC,
        simS, 1048576, NONE, kN2, 63, 6, 0.125f, nullptr, nullptr, 0, nullptr, 0);

    // Phase 5: scores. reg -> S -> softmax_cast -> p_reg; cls -> S
    hgemm_nt<0, 0, 0, 0><<<dim3(16, 4, 8), 256, 0, stream>>>(kHD, 1,
        qn + 524288, 128, NONE, kC, kn + 2097152, 128, NONE, kC,
        S, 1048576, NONE, kN2, 63, 6, 25.f, nullptr, nullptr, 0, nullptr, 0);
    softmax_cast<<<4096, 256, 0, stream>>>(S, p_reg);
    hgemm_nt<0, 1, 0, 0><<<dim3(16, 4, 8), 256, 0, stream>>>(kHD, 1,
        qn, 128, NONE, kC, kn, 128, NONE, kC,
        S, 1048576, NONE, kN2, 63, 6, 25.f, cls_score, nullptr, 0, nullptr, 0);

    // Phase 6: fused cls-softmax + blend + head-mean + round2 weights
    sb_kernel<<<512, 256, 0, stream>>>(S, p_reg, simS, regS, attn_h, w_c, w_r);

    // Phase 7: attn @ V, z=16 (8 heads x cls|reg), SK=8 -> xcat32
    hgemm_nt<2, 0, 0, 0><<<dim3(1, 4, 128), 256, 0, stream>>>(kN2, 8,
        attn_h, 1048576, NONE, kN2, vT, 262144, 2097152, kN2,
        xcat32, 128, 524288, kC, 7, 3, 1.f, nullptr, nullptr, 0, nullptr, 0);
    build_xcat<<<8192, 256, 0, stream>>>(xcat32, kvh, xcat16);

    // Phase 8: output linears -> out cols [1024,3072), z=2, SK=4, bias
    hgemm_nt<2, 0, 1, 0><<<dim3(16, 4, 8), 256, 0, stream>>>(kC2, 4,
        xcat16, 1048576, NONE, kC2, WlinT, 4194304, NONE, kC2,
        out + kC, (long)kN1 * kC3, NONE, kC3, 63, 6, 1.f, nullptr, biasWS, kC2, nullptr, 0);

    // Phase 9: ave features -> out cols [0,1024), z=2, SK=8
    hgemm_nt<2, 0, 0, 0><<<dim3(8, 4, 16), 256, 0, stream>>>(kN2, 8,
        w_c, 1048576, NONE, kN2, vT, 2097152, NONE, kN2,
        out, (long)kN1 * kC3, NONE, kC3, 63, 6, 1.f, nullptr, nullptr, 0, nullptr, 0);
}

// Round 5
// 442.999 us; speedup vs baseline: 3.5314x; 1.0292x over previous
//
#include <hip/hip_runtime.h>

// Problem constants (B=1)
constexpr int kN1 = 512;
constexpr int kN2 = 2048;
constexpr int kC  = 1024;
constexpr int kH  = 8;
constexpr int kHD = 128;
constexpr int kC2 = 2048;
constexpr int kC3 = 3072;

typedef _Float16 half8 __attribute__((ext_vector_type(8)));
typedef _Float16 half4v __attribute__((ext_vector_type(4)));
typedef float f32x4 __attribute__((ext_vector_type(4)));

// async global->LDS, 16 B per lane; LDS dest is wave-uniform base + lane*16
#define GLD16(gptr, lptr) \
    __builtin_amdgcn_global_load_lds((const __attribute__((address_space(1))) void*)(gptr), \
                                     (__attribute__((address_space(3))) void*)(lptr), 16, 0, 0)

// s_waitcnt immediates: vmcnt [3:0]|[15:14], expcnt [6:4], lgkmcnt [11:8]
#define WAIT_VM4   0x0F74  // vmcnt(4)
#define WAIT_VM0   0x0F70  // vmcnt(0)
#define WAIT_LGKM0 0xC07F  // lgkmcnt(0)

// ---------------------------------------------------------------------------
// fp16 NT MFMA GEMM, double-buffered (raw s_barrier + manual vmcnt),
// z-batching with (h,g) decomposition, split-K.
//   OUTK: 0 fp32 store, 1 fp16 store, 2 fp32 unsafeAtomicAdd (dest pre-zeroed,
//         bias only on s==0 splits)
//   zz = blockIdx.z / SK; h = zz & hmask; g = zz >> hshift.
//   A += h*sAz + g*sAz2; B += h*sBz + g*sBz2; Coff = h*sCz + g*sCz2.
// Tile 128x128, BK=32, 256 threads, 32 KB LDS (2 buffers).
// ---------------------------------------------------------------------------
template<int OUTK, int COLSCALE, int BIAS>
__global__ __launch_bounds__(256)
void hgemm_nt(int K, int SK,
              const _Float16* __restrict__ A, long sAz, long sAz2, int lda,
              const _Float16* __restrict__ B, long sBz, long sBz2, int ldb,
              void* __restrict__ Cv, long sCz, long sCz2, int ldc,
              int hmask, int hshift, float alpha,
              const float* __restrict__ colScale,
              const float* __restrict__ bias, long biasZ)
{
    __shared__ uint4 smem[2048];              // 32 KB: 2 x (A 8 KB | B 8 KB)
    char* smembase = (char*)smem;
    const int tid = threadIdx.x;
    const int w = tid >> 6, l = tid & 63;
    const int m0 = blockIdx.y << 7, n0 = blockIdx.x << 7;
    const int wm = (w >> 1) << 6, wn = (w & 1) << 6;
    const int kq = l >> 4, lm = l & 15;

    const int bz = blockIdx.z;
    const int zz = bz / SK, s = bz - zz * SK;
    const int h = zz & hmask, g = zz >> hshift;
    A += (long)h * sAz + (long)g * sAz2;
    B += (long)h * sBz + (long)g * sBz2;
    const long Coff = (long)h * sCz + (long)g * sCz2;
    const int kper = K / SK, kbeg = s * kper;
    const int nIter = kper >> 5;

    const int skq = w >> 1;
    const int sr0 = (w & 1) << 6;
    const _Float16* gA = A + (long)(m0 + sr0 + l) * lda + skq * 8 + kbeg;
    const _Float16* gB = B + (long)(n0 + sr0 + l) * ldb + skq * 8 + kbeg;
    const int soff = skq * 2048 + (sr0 + l) * 16;

    auto stage = [&](int it, int b) {
        char* dst = smembase + b * 16384;
        const int k0 = it << 5;
        GLD16(gA + k0,      dst + soff);
        GLD16(gA + k0 + 16, dst + soff + 4096);
        GLD16(gB + k0,      dst + 8192 + soff);
        GLD16(gB + k0 + 16, dst + 8192 + soff + 4096);
    };

    f32x4 acc[4][4] = {};
    stage(0, 0);

    for (int it = 0; it < nIter; ++it) {
        const int cur = it & 1;
        const bool hasNext = (it + 1 < nIter);
        if (hasNext) stage(it + 1, cur ^ 1);
        if (hasNext) __builtin_amdgcn_s_waitcnt(WAIT_VM4);
        else         __builtin_amdgcn_s_waitcnt(WAIT_VM0);
        __builtin_amdgcn_s_barrier();
        const char* cbase = smembase + cur * 16384;
        half8 af[4], bfr[4];
        const char* pa = cbase + kq * 2048 + (wm + lm) * 16;
        const char* pb = cbase + 8192 + kq * 2048 + (wn + lm) * 16;
        #pragma unroll
        for (int i = 0; i < 4; ++i) {
            af[i]  = *(const half8*)(pa + i * 256);
            bfr[i] = *(const half8*)(pb + i * 256);
        }
        #pragma unroll
        for (int mi = 0; mi < 4; ++mi)
            #pragma unroll
            for (int ni = 0; ni < 4; ++ni)
                acc[mi][ni] = __builtin_amdgcn_mfma_f32_16x16x32_f16(af[mi], bfr[ni], acc[mi][ni], 0, 0, 0);
        __builtin_amdgcn_s_waitcnt(WAIT_LGKM0);
        __builtin_amdgcn_s_barrier();
    }

    // C/D layout: col = lane&15, row = (lane>>4)*4 + reg
    const int rbase = m0 + wm + kq * 4;
    const float* bz_bias = BIAS ? bias + zz * biasZ : nullptr;
    #pragma unroll
    for (int mi = 0; mi < 4; ++mi) {
        #pragma unroll
        for (int ni = 0; ni < 4; ++ni) {
            const int col = n0 + wn + ni * 16 + lm;
            const float cs = COLSCALE ? colScale[col] : 1.f;
            const float bs = BIAS ? bz_bias[col] : 0.f;
            #pragma unroll
            for (int r = 0; r < 4; ++r) {
                const long row = rbase + mi * 16 + r;
                float v = acc[mi][ni][r] * alpha;
                if (COLSCALE) v *= cs;
                if (BIAS && (OUTK != 2 || s == 0)) v += bs;
                const long off = Coff + row * ldc + col;
                if (OUTK == 0)      ((float*)Cv)[off] = v;
                else if (OUTK == 1) ((_Float16*)Cv)[off] = (_Float16)v;
                else                unsafeAtomicAdd(&((float*)Cv)[off], v);
            }
        }
    }
}

// ---------------------------------------------------------------------------
// fp32 -> fp16 cast, z picks (x_cls | x_reg) -> d[z]
// ---------------------------------------------------------------------------
__global__ __launch_bounds__(256)
void cast_f2h(const float* __restrict__ s0, const float* __restrict__ s1,
              _Float16* __restrict__ d, int n4)
{
    const int i = blockIdx.x * 256 + threadIdx.x;
    const float* s = blockIdx.y ? s1 : s0;
    const float4 v = ((const float4*)s)[i];
    half4v o;
    o.x = (_Float16)v.x; o.y = (_Float16)v.y; o.z = (_Float16)v.z; o.w = (_Float16)v.w;
    ((half4v*)(d + (size_t)blockIdx.y * n4 * 4))[i] = o;
}

// ---------------------------------------------------------------------------
// Transpose-cast: dst[z][n][k] = src_z[k][n]. Grid (N/32, K/32, 2).
// srcZoff: element offset applied per z to a single base pointer (s1 null)
// ---------------------------------------------------------------------------
template<typename T>
__global__ __launch_bounds__(256)
void transpose_h(const T* __restrict__ s0, const T* __restrict__ s1,
                 long srcZoff, int ldsrc,
                 _Float16* __restrict__ dst, long dstZ, int lddst)
{
    __shared__ float t[32][33];
    const T* src = s1 ? (blockIdx.z ? s1 : s0) : s0 + (long)blockIdx.z * srcZoff;
    _Float16* d = dst + (long)blockIdx.z * dstZ;
    const int n0 = blockIdx.x << 5, k0 = blockIdx.y << 5;
    const int tx = threadIdx.x & 31, ty = threadIdx.x >> 5;
    #pragma unroll
    for (int j = ty; j < 32; j += 8)
        t[j][tx] = (float)src[(size_t)(k0 + j) * ldsrc + n0 + tx];
    __syncthreads();
    #pragma unroll
    for (int j = ty; j < 32; j += 8)
        d[(size_t)(n0 + j) * lddst + k0 + tx] = (_Float16)t[tx][j];
}

// ---------------------------------------------------------------------------
// Wave-per-vector L2 norms (128-elem vectors, 2 elems/lane, shuffle reduce)
// ---------------------------------------------------------------------------
__global__ __launch_bounds__(256)
void headnorm_q(const float* __restrict__ qh32, _Float16* __restrict__ qn)
{
    const int vid = blockIdx.x * 4 + (threadIdx.x >> 6);   // [0, 8192)
    const int lane = threadIdx.x & 63;
    const int g = vid >> 12, rr = vid & 4095, row = rr >> 3, hh = rr & 7;
    const size_t o = (size_t)g * 524288 + (size_t)row * 1024 + hh * 128 + lane * 2;
    const float2 v = *(const float2*)(qh32 + o);
    float ss = v.x * v.x + v.y * v.y;
    #pragma unroll
    for (int d = 32; d > 0; d >>= 1) ss += __shfl_xor(ss, d, 64);
    const float inv = rsqrtf(ss);
    _Float16* dp = qn + o;
    dp[0] = (_Float16)(v.x * inv); dp[1] = (_Float16)(v.y * inv);
}

__global__ __launch_bounds__(256)
void headnorm_kv(const _Float16* __restrict__ kvh,
                 _Float16* __restrict__ kn, _Float16* __restrict__ vn)
{
    const int vid = blockIdx.x * 4 + (threadIdx.x >> 6);   // [0, 65536)
    const int lane = threadIdx.x & 63;
    const int half_ = vid >> 15;                // 0 = K, 1 = V
    const int r15 = vid & 32767;
    const int g = r15 >> 14, rr = r15 & 16383, row = rr >> 3, hh = rr & 7;
    const _Float16* sp = kvh + (size_t)g * 4194304 + (size_t)row * 2048
                             + half_ * 1024 + hh * 128 + lane * 2;
    const float a = (float)sp[0], b = (float)sp[1];
    float ss = a * a + b * b;
    #pragma unroll
    for (int d = 32; d > 0; d >>= 1) ss += __shfl_xor(ss, d, 64);
    const float inv = rsqrtf(ss);
    _Float16* dp = (half_ ? vn : kn) + (size_t)g * 2097152 + (size_t)row * 1024
                                     + hh * 128 + lane * 2;
    dp[0] = (_Float16)(a * inv); dp[1] = (_Float16)(b * inv);
}

// ---------------------------------------------------------------------------
// Block reduce (256 threads, 4 waves). OP: 0 sum, 1 max
// ---------------------------------------------------------------------------
template<int OP>
__device__ __forceinline__ float bred(float v, float* lds)
{
    #pragma unroll
    for (int o = 32; o > 0; o >>= 1) {
        const float u = __shfl_xor(v, o, 64);
        v = OP ? fmaxf(v, u) : v + u;
    }
    __syncthreads();
    if ((threadIdx.x & 63) == 0) lds[threadIdx.x >> 6] = v;
    __syncthreads();
    return OP ? fmaxf(fmaxf(lds[0], lds[1]), fmaxf(lds[2], lds[3]))
              : lds[0] + lds[1] + lds[2] + lds[3];
}

// ---------------------------------------------------------------------------
// Fused: per q row — for each head: softmax(Sreg), softmax(Scls), blend,
// write fp16 attn, accumulate head-mean; then round-2 masked renorm weights.
// ---------------------------------------------------------------------------
__global__ __launch_bounds__(256)
void sb2_kernel(const _Float16* __restrict__ Sc, const _Float16* __restrict__ Sr,
                const float* __restrict__ simS, const float* __restrict__ regS,
                _Float16* __restrict__ attn,
                _Float16* __restrict__ wc, _Float16* __restrict__ wr)
{
    __shared__ float lds[4];
    const int q = blockIdx.x, t = threadIdx.x;
    float asum[8] = {};
    for (int hh = 0; hh < 8; ++hh) {
        const size_t rb = (size_t)(hh * 512 + q) * 2048;
        float vc[8], vr[8];
        float mc = -1e30f, mr = -1e30f;
        #pragma unroll
        for (int j = 0; j < 8; ++j) {
            vc[j] = (float)Sc[rb + t + 256 * j];
            vr[j] = (float)Sr[rb + t + 256 * j];
            mc = fmaxf(mc, vc[j]); mr = fmaxf(mr, vr[j]);
        }
        mc = bred<1>(mc, lds);
        mr = bred<1>(mr, lds);
        float sc = 0.f, sr = 0.f;
        #pragma unroll
        for (int j = 0; j < 8; ++j) {
            vc[j] = expf(vc[j] - mc); sc += vc[j];
            vr[j] = expf(vr[j] - mr); sr += vr[j];
        }
        sc = bred<0>(sc, lds);
        sr = bred<0>(sr, lds);
        const float ic = 0.5f / sc, ir = 0.5f / sr;
        #pragma unroll
        for (int j = 0; j < 8; ++j) {
            const float a = vc[j] * ic + vr[j] * ir;
            attn[rb + t + 256 * j] = (_Float16)a;
            asum[j] += a;
        }
    }
    float mx = -1e30f;
    #pragma unroll
    for (int j = 0; j < 8; ++j) { asum[j] *= 0.125f; mx = fmaxf(mx, asum[j]); }
    mx = bred<1>(mx, lds);
    float em[8], emo[8];
    float s1 = 0.f, s2 = 0.f;
    const size_t qb = (size_t)q * 2048;
    #pragma unroll
    for (int j = 0; j < 8; ++j) {
        const float e = expf(asum[j] - mx);
        const float m  = simS[qb + t + 256 * j] > 0.75f ? 1.f : 0.f;
        const float mo = regS[qb + t + 256 * j] > 0.99f ? 1.f : 0.f;
        em[j] = e * m; emo[j] = e * m * mo;
        s1 += em[j]; s2 += emo[j];
    }
    s1 = bred<0>(s1, lds);
    s2 = bred<0>(s2, lds);
    const float i1 = 1.f / s1, i2 = 1.f / s2;
    #pragma unroll
    for (int j = 0; j < 8; ++j) {
        wc[qb + t + 256 * j] = (_Float16)(em[j] * i1);
        wr[qb + t + 256 * j] = (_Float16)(emo[j] * i2);
    }
}

// ---------------------------------------------------------------------------
// Build xcat16 [2][512][2048]: cols<1024 from xcat32, cols>=1024 from kvh V.
// ---------------------------------------------------------------------------
__global__ __launch_bounds__(256)
void build_xcat(const float* __restrict__ xc32, const _Float16* __restrict__ kvh,
                _Float16* __restrict__ xcat)
{
    const int idx = blockIdx.x * 256 + threadIdx.x;   // 2*512*2048
    const int j = idx & 2047;
    const int n = (idx >> 11) & 511;
    const int g = idx >> 20;
    _Float16 v;
    if (j < 1024) v = (_Float16)xc32[(g << 19) + (n << 10) + j];
    else          v = kvh[(size_t)g * 4194304 + (size_t)n * 2048 + j];
    xcat[idx] = v;
}

extern "C" void kernel_launch(void* const* d_in, const int* in_sizes, int n_in,
                              void* d_out, int out_size, void* d_ws, size_t ws_size,
                              hipStream_t stream)
{
    const float* x_cls     = (const float*)d_in[0];
    const float* x_reg     = (const float*)d_in[1];
    const float* cls_score = (const float*)d_in[2];
    const float* W_q_cls   = (const float*)d_in[4];
    const float* W_kv_cls  = (const float*)d_in[5];
    const float* W_q_reg   = (const float*)d_in[6];
    const float* W_kv_reg  = (const float*)d_in[7];
    const float* W_lin     = (const float*)d_in[8];
    const float* b_lin     = (const float*)d_in[9];
    const float* W_lin_reg = (const float*)d_in[10];
    const float* b_lin_reg = (const float*)d_in[11];
    float* out = (float*)d_out;

    if (ws_size < (size_t)127 * 1048576) return;

    // Workspace overlay (MiB offsets), peak 127 MiB:
    char* W = (char*)d_ws;
    auto at = [&](size_t mb) { return (void*)(W + mb * 1048576); };
    _Float16* WlinT  = (_Float16*)at(0);    // [2][2048x2048]
    _Float16* kvh    = (_Float16*)at(16);   // [2][2048x2048] (K|V)
    _Float16* vT     = (_Float16*)at(32);   // [2][1024x2048]
    float*    qh32   = (float*)at(40);      // [2][512x1024]; xcat32 reuses
    float*    xcat32 = (float*)at(40);
    float*    biasWS = (float*)at(44);      // [2][2048]
    _Float16* xbf    = (_Float16*)at(45);   // [2][2048x1024]; xcat16 reuses
    _Float16* xcat16 = (_Float16*)at(45);
    _Float16* WqT    = (_Float16*)at(53);   // [2][1024x1024]
    _Float16* WkvT   = (_Float16*)at(57);   // [2][2048x1024]
    _Float16* qn     = (_Float16*)at(65);   // [2][512x1024]
    _Float16* kn     = (_Float16*)at(67);   // [2][2048x1024]
    _Float16* attn_h = (_Float16*)at(67);   // [8x512x2048] (over kn+vn, dead)
    _Float16* vn     = (_Float16*)at(75);   // [2][2048x1024]
    float*    simS   = (float*)at(83);      // [512x2048]
    float*    regS   = (float*)at(87);      // [512x2048]
    _Float16* S16c   = (_Float16*)at(91);   // [8x512x2048] fp16 cls scores
    _Float16* S16r   = (_Float16*)at(107);  // [8x512x2048] fp16 reg scores
    _Float16* w_c    = (_Float16*)at(123);  // [512x2048]
    _Float16* w_r    = (_Float16*)at(125);

    const long NONE = 0;

    hipMemsetAsync(d_out, 0, (size_t)out_size * 4, stream);
    hipMemsetAsync(qh32, 0, (size_t)4 * 1048576, stream);
    hipMemsetAsync(simS, 0, (size_t)8 * 1048576, stream);   // simS+regS
    hipMemcpyAsync(biasWS,       b_lin,     kC2 * 4, hipMemcpyDeviceToDevice, stream);
    hipMemcpyAsync(biasWS + kC2, b_lin_reg, kC2 * 4, hipMemcpyDeviceToDevice, stream);

    // Phase 1: prep
    cast_f2h<<<dim3(2048, 2), 256, 0, stream>>>(x_cls, x_reg, xbf, 524288);
    transpose_h<float><<<dim3(32, 32, 2), 256, 0, stream>>>(W_q_cls, W_q_reg, 0, kC, WqT, 1048576, kC);
    transpose_h<float><<<dim3(64, 32, 2), 256, 0, stream>>>(W_kv_cls, W_kv_reg, 0, kC2, WkvT, 2097152, kC);
    transpose_h<float><<<dim3(64, 64, 2), 256, 0, stream>>>(W_lin, W_lin_reg, 0, kC2, WlinT, 4194304, kC2);

    // Phase 2: projections. q: SK=8 atomic; kv: SK=1 fp16 (no epilogue scatter)
    hgemm_nt<2, 0, 0><<<dim3(8, 4, 16), 256, 0, stream>>>(kC, 8,
        xbf, 2097152, NONE, kC, WqT, 1048576, NONE, kC,
        qh32, 524288, NONE, kC, 63, 6, 1.f, nullptr, nullptr, 0);
    hgemm_nt<1, 0, 0><<<dim3(16, 16, 2), 256, 0, stream>>>(kC, 1,
        xbf, 2097152, NONE, kC, WkvT, 2097152, NONE, kC,
        kvh, 4194304, NONE, kC2, 63, 6, 1.f, nullptr, nullptr, 0);

    // Phase 3: coalesced V^T + norms
    transpose_h<_Float16><<<dim3(32, 64, 2), 256, 0, stream>>>(kvh + kC, nullptr,
        4194304, kC2, vT, 2097152, kN2);
    headnorm_q<<<2048, 256, 0, stream>>>(qh32, qn);
    headnorm_kv<<<16384, 256, 0, stream>>>(kvh, kn, vn);
    hipMemsetAsync(xcat32, 0, (size_t)4 * 1048576, stream);  // qh32 now free

    // Phase 4: v-v similarity (head-sum/8), z=2, SK=4
    hgemm_nt<2, 0, 0><<<dim3(16, 4, 8), 256, 0, stream>>>(kC, 4,
        vn, 2097152, NONE, kC, vn, 2097152, NONE, kC,
        simS, 1048576, NONE, kN2, 63, 6, 0.125f, nullptr, nullptr, 0);

    // Phase 5: scores -> fp16 (z=8 heads each; cls gets per-key colScale)
    hgemm_nt<1, 1, 0><<<dim3(16, 4, 8), 256, 0, stream>>>(kHD, 1,
        qn, 128, NONE, kC, kn, 128, NONE, kC,
        S16c, 1048576, NONE, kN2, 7, 3, 25.f, cls_score, nullptr, 0);
    hgemm_nt<1, 0, 0><<<dim3(16, 4, 8), 256, 0, stream>>>(kHD, 1,
        qn + 524288, 128, NONE, kC, kn + 2097152, 128, NONE, kC,
        S16r, 1048576, NONE, kN2, 7, 3, 25.f, nullptr, nullptr, 0);

    // Phase 6: fused dual softmax + blend + head-mean + round2 weights
    sb2_kernel<<<512, 256, 0, stream>>>(S16c, S16r, simS, regS, attn_h, w_c, w_r);

    // Phase 7: attn @ V, z=16 (8 heads x cls|reg), SK=8 -> xcat32
    hgemm_nt<2, 0, 0><<<dim3(1, 4, 128), 256, 0, stream>>>(kN2, 8,
        attn_h, 1048576, NONE, kN2, vT, 262144, 2097152, kN2,
        xcat32, 128, 524288, kC, 7, 3, 1.f, nullptr, nullptr, 0);
    build_xcat<<<8192, 256, 0, stream>>>(xcat32, kvh, xcat16);

    // Phase 8: output linears -> out cols [1024,3072), z=2, SK=4, bias
    hgemm_nt<2, 0, 1><<<dim3(16, 4, 8), 256, 0, stream>>>(kC2, 4,
        xcat16, 1048576, NONE, kC2, WlinT, 4194304, NONE, kC2,
        out + kC, (long)kN1 * kC3, NONE, kC3, 63, 6, 1.f, nullptr, biasWS, kC2);

    // Phase 9: ave features -> out cols [0,1024), z=2, SK=8
    hgemm_nt<2, 0, 0><<<dim3(8, 4, 16), 256, 0, stream>>>(kN2, 8,
        w_c, 1048576, NONE, kN2, vT, 2097152, NONE, kN2,
        out, (long)kN1 * kC3, NONE, kC3, 63, 6, 1.f, nullptr, nullptr, 0);
}

// Round 6
// 342.200 us; speedup vs baseline: 4.5716x; 1.2946x over previous
//
#include <hip/hip_runtime.h>

// Problem constants (B=1)
constexpr int kN1 = 512;
constexpr int kN2 = 2048;
constexpr int kC  = 1024;
constexpr int kHD = 128;
constexpr int kC2 = 2048;
constexpr int kC3 = 3072;

typedef _Float16 half8 __attribute__((ext_vector_type(8)));
typedef _Float16 half4v __attribute__((ext_vector_type(4)));
typedef float f32x4 __attribute__((ext_vector_type(4)));

// async global->LDS, 16 B per lane; LDS dest is wave-uniform base + lane*16
#define GLD16(gptr, lptr) \
    __builtin_amdgcn_global_load_lds((const __attribute__((address_space(1))) void*)(gptr), \
                                     (__attribute__((address_space(3))) void*)(lptr), 16, 0, 0)

// s_waitcnt immediates: vmcnt [3:0]|[15:14], expcnt [6:4], lgkmcnt [11:8]
#define WAIT_VM8   0x0F78  // vmcnt(8)
#define WAIT_VM4   0x0F74  // vmcnt(4)
#define WAIT_VM0   0x0F70  // vmcnt(0)
#define WAIT_LGKM0 0xC07F  // lgkmcnt(0)

// ---------------------------------------------------------------------------
// fp16 NT MFMA GEMM, triple-buffered (prefetch distance 2, vmcnt(8) steady),
// z-batching via (h,g) decomposition, split-K to separate partial buffers.
//   OUTK: 0 fp32 store, 1 fp16 store (no atomics anywhere)
//   COLSCALE: 0 none, 1 always, 2 only when g==0 (merged cls|reg scores)
//   AHX: h = blockIdx.x (head folded into the N dimension; sCz must be 0)
//   zz = blockIdx.z / SK; s = blockIdx.z % SK;
//   h = AHX ? blockIdx.x : zz & hmask; g = AHX ? zz : zz >> hshift.
//   A += h*sAz + g*sAz2; B += h*sBz + g*sBz2; Coff = s*sSplit + h*sCz + g*sCz2
// Tile 128x128, BK=32, 256 threads, 48 KB LDS (3 buffers).
// ---------------------------------------------------------------------------
template<int OUTK, int COLSCALE, int AHX>
__global__ __launch_bounds__(256)
void hgemm_nt(int K, int SK,
              const _Float16* __restrict__ A, long sAz, long sAz2, int lda,
              const _Float16* __restrict__ B, long sBz, long sBz2, int ldb,
              void* __restrict__ Cv, long sSplit, long sCz, long sCz2, int ldc,
              int hmask, int hshift, float alpha,
              const float* __restrict__ colScale)
{
    __shared__ uint4 smem[3072];              // 48 KB: 3 x (A 8 KB | B 8 KB)
    char* smembase = (char*)smem;
    const int tid = threadIdx.x;
    const int w = tid >> 6, l = tid & 63;
    const int m0 = blockIdx.y << 7, n0 = blockIdx.x << 7;
    const int wm = (w >> 1) << 6, wn = (w & 1) << 6;
    const int kq = l >> 4, lm = l & 15;

    const int bz = blockIdx.z;
    const int zz = bz / SK, s = bz - zz * SK;
    const int h = AHX ? (int)blockIdx.x : (zz & hmask);
    const int g = AHX ? zz : (zz >> hshift);
    A += (long)h * sAz + (long)g * sAz2;
    B += (long)h * sBz + (long)g * sBz2;
    const long Coff = (long)s * sSplit + (long)h * sCz + (long)g * sCz2;
    const int kper = K / SK, kbeg = s * kper;
    const int nIter = kper >> 5;

    const int skq = w >> 1;
    const int sr0 = (w & 1) << 6;
    const _Float16* gA = A + (long)(m0 + sr0 + l) * lda + skq * 8 + kbeg;
    const _Float16* gB = B + (long)(n0 + sr0 + l) * ldb + skq * 8 + kbeg;
    const int soff = skq * 2048 + (sr0 + l) * 16;

    auto stage = [&](int it, int b) {
        char* dst = smembase + b * 16384;
        const int k0 = it << 5;
        GLD16(gA + k0,      dst + soff);
        GLD16(gA + k0 + 16, dst + soff + 4096);
        GLD16(gB + k0,      dst + 8192 + soff);
        GLD16(gB + k0 + 16, dst + 8192 + soff + 4096);
    };

    f32x4 acc[4][4] = {};
    stage(0, 0);
    if (nIter > 1) stage(1, 1);

    int bufc = 0;
    for (int it = 0; it < nIter; ++it) {
        if (it + 2 < nIter) {
            int b2 = bufc + 2; if (b2 >= 3) b2 -= 3;
            stage(it + 2, b2);
            __builtin_amdgcn_s_waitcnt(WAIT_VM8);   // oldest tile's loads done
        } else if (it + 1 < nIter) {
            __builtin_amdgcn_s_waitcnt(WAIT_VM4);
        } else {
            __builtin_amdgcn_s_waitcnt(WAIT_VM0);
        }
        __builtin_amdgcn_s_barrier();               // all waves' tile-it loads in
        const char* cbase = smembase + bufc * 16384;
        half8 af[4], bfr[4];
        const char* pa = cbase + kq * 2048 + (wm + lm) * 16;
        const char* pb = cbase + 8192 + kq * 2048 + (wn + lm) * 16;
        #pragma unroll
        for (int i = 0; i < 4; ++i) {
            af[i]  = *(const half8*)(pa + i * 256);
            bfr[i] = *(const half8*)(pb + i * 256);
        }
        #pragma unroll
        for (int mi = 0; mi < 4; ++mi)
            #pragma unroll
            for (int ni = 0; ni < 4; ++ni)
                acc[mi][ni] = __builtin_amdgcn_mfma_f32_16x16x32_f16(af[mi], bfr[ni], acc[mi][ni], 0, 0, 0);
        __builtin_amdgcn_s_waitcnt(WAIT_LGKM0);     // own reads of buf retired
        __builtin_amdgcn_s_barrier();               // all waves done reading buf
        if (++bufc == 3) bufc = 0;
    }

    // C/D layout: col = lane&15, row = (lane>>4)*4 + reg
    const int rbase = m0 + wm + kq * 4;
    #pragma unroll
    for (int mi = 0; mi < 4; ++mi) {
        #pragma unroll
        for (int ni = 0; ni < 4; ++ni) {
            const int col = n0 + wn + ni * 16 + lm;
            float cs = alpha;
            if (COLSCALE == 1 || (COLSCALE == 2 && g == 0)) cs *= colScale[col];
            #pragma unroll
            for (int r = 0; r < 4; ++r) {
                const long row = rbase + mi * 16 + r;
                const float v = acc[mi][ni][r] * cs;
                const long off = Coff + row * ldc + col;
                if (OUTK == 0) ((float*)Cv)[off] = v;
                else           ((_Float16*)Cv)[off] = (_Float16)v;
            }
        }
    }
}

// ---------------------------------------------------------------------------
// fp32 -> fp16 cast, z picks (x_cls | x_reg) -> d[z]
// ---------------------------------------------------------------------------
__global__ __launch_bounds__(256)
void cast_f2h(const float* __restrict__ s0, const float* __restrict__ s1,
              _Float16* __restrict__ d, int n4)
{
    const int i = blockIdx.x * 256 + threadIdx.x;
    const float* s = blockIdx.y ? s1 : s0;
    const float4 v = ((const float4*)s)[i];
    half4v o;
    o.x = (_Float16)v.x; o.y = (_Float16)v.y; o.z = (_Float16)v.z; o.w = (_Float16)v.w;
    ((half4v*)(d + (size_t)blockIdx.y * n4 * 4))[i] = o;
}

// ---------------------------------------------------------------------------
// Transpose-cast: dst[z][n][k] = src_z[k][n]. Grid (N/32, K/32, 2).
// srcZoff: element offset per z on a single base pointer (when s1 null)
// ---------------------------------------------------------------------------
template<typename T>
__global__ __launch_bounds__(256)
void transpose_h(const T* __restrict__ s0, const T* __restrict__ s1,
                 long srcZoff, int ldsrc,
                 _Float16* __restrict__ dst, long dstZ, int lddst)
{
    __shared__ float t[32][33];
    const T* src = s1 ? (blockIdx.z ? s1 : s0) : s0 + (long)blockIdx.z * srcZoff;
    _Float16* d = dst + (long)blockIdx.z * dstZ;
    const int n0 = blockIdx.x << 5, k0 = blockIdx.y << 5;
    const int tx = threadIdx.x & 31, ty = threadIdx.x >> 5;
    #pragma unroll
    for (int j = ty; j < 32; j += 8)
        t[j][tx] = (float)src[(size_t)(k0 + j) * ldsrc + n0 + tx];
    __syncthreads();
    #pragma unroll
    for (int j = ty; j < 32; j += 8)
        d[(size_t)(n0 + j) * lddst + k0 + tx] = (_Float16)t[tx][j];
}

// ---------------------------------------------------------------------------
// q-norm fused with 4-way split-K reduce. qpart [4][2][512][1024] fp32.
// ---------------------------------------------------------------------------
__global__ __launch_bounds__(256)
void headnorm_q(const float* __restrict__ qpart, _Float16* __restrict__ qn)
{
    const int vid = blockIdx.x * 4 + (threadIdx.x >> 6);   // [0, 8192)
    const int lane = threadIdx.x & 63;
    const int g = vid >> 12, rr = vid & 4095, row = rr >> 3, hh = rr & 7;
    const size_t o = (size_t)g * 524288 + (size_t)row * 1024 + hh * 128 + lane * 2;
    float2 v = *(const float2*)(qpart + o);
    #pragma unroll
    for (int s = 1; s < 4; ++s) {
        const float2 p = *(const float2*)(qpart + (size_t)s * 1048576 + o);
        v.x += p.x; v.y += p.y;
    }
    float ss = v.x * v.x + v.y * v.y;
    #pragma unroll
    for (int d = 32; d > 0; d >>= 1) ss += __shfl_xor(ss, d, 64);
    const float inv = rsqrtf(ss);
    _Float16* dp = qn + o;
    dp[0] = (_Float16)(v.x * inv); dp[1] = (_Float16)(v.y * inv);
}

__global__ __launch_bounds__(256)
void headnorm_kv(const _Float16* __restrict__ kvh,
                 _Float16* __restrict__ kn, _Float16* __restrict__ vn)
{
    const int vid = blockIdx.x * 4 + (threadIdx.x >> 6);   // [0, 65536)
    const int lane = threadIdx.x & 63;
    const int half_ = vid >> 15;                // 0 = K, 1 = V
    const int r15 = vid & 32767;
    const int g = r15 >> 14, rr = r15 & 16383, row = rr >> 3, hh = rr & 7;
    const _Float16* sp = kvh + (size_t)g * 4194304 + (size_t)row * 2048
                             + half_ * 1024 + hh * 128 + lane * 2;
    const float a = (float)sp[0], b = (float)sp[1];
    float ss = a * a + b * b;
    #pragma unroll
    for (int d = 32; d > 0; d >>= 1) ss += __shfl_xor(ss, d, 64);
    const float inv = rsqrtf(ss);
    _Float16* dp = (half_ ? vn : kn) + (size_t)g * 2097152 + (size_t)row * 1024
                                     + hh * 128 + lane * 2;
    dp[0] = (_Float16)(a * inv); dp[1] = (_Float16)(b * inv);
}

// ---------------------------------------------------------------------------
// Block reduce (256 threads, 4 waves). OP: 0 sum, 1 max
// ---------------------------------------------------------------------------
template<int OP>
__device__ __forceinline__ float bred(float v, float* lds)
{
    #pragma unroll
    for (int o = 32; o > 0; o >>= 1) {
        const float u = __shfl_xor(v, o, 64);
        v = OP ? fmaxf(v, u) : v + u;
    }
    __syncthreads();
    if ((threadIdx.x & 63) == 0) lds[threadIdx.x >> 6] = v;
    __syncthreads();
    return OP ? fmaxf(fmaxf(lds[0], lds[1]), fmaxf(lds[2], lds[3]))
              : lds[0] + lds[1] + lds[2] + lds[3];
}

// ---------------------------------------------------------------------------
// Fused: per q row — dual softmax per head + blend -> fp16 attn + head-mean,
// then round-2 masked renorm weights. v-sim split-K partials reduced inline.
// S16 [16][512][2048] fp16 (z 0-7 cls, 8-15 reg); simPart [2][2][512][2048].
// ---------------------------------------------------------------------------
__global__ __launch_bounds__(256)
void sb2_kernel(const _Float16* __restrict__ S16, const float* __restrict__ simPart,
                _Float16* __restrict__ attn,
                _Float16* __restrict__ wc, _Float16* __restrict__ wr)
{
    __shared__ float lds[4];
    const int q = blockIdx.x, t = threadIdx.x;
    float asum[8] = {};
    for (int hh = 0; hh < 8; ++hh) {
        const size_t rb = (size_t)(hh * 512 + q) * 2048;
        float vc[8], vr[8];
        float mc = -1e30f, mr = -1e30f;
        #pragma unroll
        for (int j = 0; j < 8; ++j) {
            vc[j] = (float)S16[rb + t + 256 * j];
            vr[j] = (float)S16[8388608 + rb + t + 256 * j];
            mc = fmaxf(mc, vc[j]); mr = fmaxf(mr, vr[j]);
        }
        mc = bred<1>(mc, lds);
        mr = bred<1>(mr, lds);
        float sc = 0.f, sr = 0.f;
        #pragma unroll
        for (int j = 0; j < 8; ++j) {
            vc[j] = expf(vc[j] - mc); sc += vc[j];
            vr[j] = expf(vr[j] - mr); sr += vr[j];
        }
        sc = bred<0>(sc, lds);
        sr = bred<0>(sr, lds);
        const float ic = 0.5f / sc, ir = 0.5f / sr;
        #pragma unroll
        for (int j = 0; j < 8; ++j) {
            const float a = vc[j] * ic + vr[j] * ir;
            attn[rb + t + 256 * j] = (_Float16)a;
            asum[j] += a;
        }
    }
    float mx = -1e30f;
    #pragma unroll
    for (int j = 0; j < 8; ++j) { asum[j] *= 0.125f; mx = fmaxf(mx, asum[j]); }
    mx = bred<1>(mx, lds);
    float em[8], emo[8];
    float s1 = 0.f, s2 = 0.f;
    const size_t qb = (size_t)q * 2048;
    #pragma unroll
    for (int j = 0; j < 8; ++j) {
        const size_t o = qb + t + 256 * j;
        const float sim = simPart[o] + simPart[2097152 + o];             // g=0
        const float reg = simPart[1048576 + o] + simPart[3145728 + o];   // g=1
        const float e = expf(asum[j] - mx);
        const float m  = sim > 0.75f ? 1.f : 0.f;
        const float mo = reg > 0.99f ? 1.f : 0.f;
        em[j] = e * m; emo[j] = e * m * mo;
        s1 += em[j]; s2 += emo[j];
    }
    s1 = bred<0>(s1, lds);
    s2 = bred<0>(s2, lds);
    const float i1 = 1.f / s1, i2 = 1.f / s2;
    #pragma unroll
    for (int j = 0; j < 8; ++j) {
        wc[qb + t + 256 * j] = (_Float16)(em[j] * i1);
        wr[qb + t + 256 * j] = (_Float16)(emo[j] * i2);
    }
}

// ---------------------------------------------------------------------------
// xcat16 [2][512][2048]: cols<1024 = 4-way reduce of attn@V partials,
// cols>=1024 = kvh V-half rows [0,512).
// ---------------------------------------------------------------------------
__global__ __launch_bounds__(256)
void build_xcat(const float* __restrict__ xcatPart, const _Float16* __restrict__ kvh,
                _Float16* __restrict__ xcat)
{
    const int idx = blockIdx.x * 256 + threadIdx.x;   // 2*512*2048
    const int j = idx & 2047;
    const int n = (idx >> 11) & 511;
    const int g = idx >> 20;
    _Float16 v;
    if (j < 1024) {
        float a = 0.f;
        #pragma unroll
        for (int s = 0; s < 4; ++s)
            a += xcatPart[(size_t)s * 1048576 + (size_t)g * 524288 + n * 1024 + j];
        v = (_Float16)a;
    } else {
        v = kvh[(size_t)g * 4194304 + (size_t)n * 2048 + j];
    }
    xcat[idx] = v;
}

// ---------------------------------------------------------------------------
// finalize: write all of d_out [2][512][3072].
// ---------------------------------------------------------------------------
__global__ __launch_bounds__(256)
void finalize(const float* __restrict__ avePart, const float* __restrict__ outPart,
              const float* __restrict__ b_lin, const float* __restrict__ b_lin_reg,
              float* __restrict__ out)
{
    const int idx = blockIdx.x * 256 + threadIdx.x;   // 2*512*3072
    const int c = idx % 3072;
    const int r = (idx / 3072) & 511;
    const int g = idx / (3072 * 512);
    float v;
    if (c < 1024) {
        v = 0.f;
        #pragma unroll
        for (int s = 0; s < 4; ++s)
            v += avePart[(size_t)s * 1048576 + (size_t)g * 524288 + r * 1024 + c];
    } else {
        const int cc = c - 1024;
        v = (g ? b_lin_reg : b_lin)[cc];
        #pragma unroll
        for (int s = 0; s < 2; ++s)
            v += outPart[(size_t)s * 2097152 + (size_t)g * 1048576 + r * 2048 + cc];
    }
    out[idx] = v;
}

extern "C" void kernel_launch(void* const* d_in, const int* in_sizes, int n_in,
                              void* d_out, int out_size, void* d_ws, size_t ws_size,
                              hipStream_t stream)
{
    const float* x_cls     = (const float*)d_in[0];
    const float* x_reg     = (const float*)d_in[1];
    const float* cls_score = (const float*)d_in[2];
    const float* W_q_cls   = (const float*)d_in[4];
    const float* W_kv_cls  = (const float*)d_in[5];
    const float* W_q_reg   = (const float*)d_in[6];
    const float* W_kv_reg  = (const float*)d_in[7];
    const float* W_lin     = (const float*)d_in[8];
    const float* b_lin     = (const float*)d_in[9];
    const float* W_lin_reg = (const float*)d_in[10];
    const float* b_lin_reg = (const float*)d_in[11];
    float* out = (float*)d_out;

    if (ws_size < (size_t)127 * 1048576) return;

    // Workspace overlay (MiB offsets), peak 126 MiB:
    char* W = (char*)d_ws;
    auto at = [&](size_t mb) { return (void*)(W + mb * 1048576); };
    _Float16* WlinT    = (_Float16*)at(0);    // ph1 -> out-lin
    _Float16* kvh      = (_Float16*)at(16);   // kv-proj -> build_xcat
    float*    outPart  = (float*)at(16);      // out-lin -> finalize (kvh dead)
    _Float16* vT       = (_Float16*)at(32);   // V^T -> ave
    float*    qpart    = (float*)at(40);      // q-proj -> headnorm_q
    _Float16* S16      = (_Float16*)at(40);   // scores -> sb2 (qpart/xbf/W*T dead)
    float*    xcatPart = (float*)at(40);      // attn@V -> build_xcat (S16 dead)
    _Float16* xbf      = (_Float16*)at(56);   // ph1 -> projections
    _Float16* xcat16   = (_Float16*)at(56);   // build_xcat -> out-lin
    _Float16* WqT      = (_Float16*)at(64);   // ph1 -> q-proj
    _Float16* WkvT     = (_Float16*)at(68);   // ph1 -> kv-proj
    _Float16* qn       = (_Float16*)at(76);   // norm -> scores
    _Float16* kn       = (_Float16*)at(78);   // norm -> scores
    _Float16* attn_h   = (_Float16*)at(78);   // sb2 -> attn@V (kn+vn dead)
    _Float16* vn       = (_Float16*)at(86);   // norm -> v-sim
    float*    avePart  = (float*)at(78);      // ave -> finalize (attn_h dead)
    float*    simPart  = (float*)at(94);      // v-sim -> sb2
    _Float16* w_c      = (_Float16*)at(110);  // sb2 -> ave
    _Float16* w_r      = (_Float16*)at(112);

    // Phase 1: prep
    cast_f2h<<<dim3(2048, 2), 256, 0, stream>>>(x_cls, x_reg, xbf, 524288);
    transpose_h<float><<<dim3(32, 32, 2), 256, 0, stream>>>(W_q_cls, W_q_reg, 0, kC, WqT, 1048576, kC);
    transpose_h<float><<<dim3(64, 32, 2), 256, 0, stream>>>(W_kv_cls, W_kv_reg, 0, kC2, WkvT, 2097152, kC);
    transpose_h<float><<<dim3(64, 64, 2), 256, 0, stream>>>(W_lin, W_lin_reg, 0, kC2, WlinT, 4194304, kC2);

    // Phase 2: projections. q: SK=4 partials; kv: direct fp16
    hgemm_nt<0, 0, 0><<<dim3(8, 4, 8), 256, 0, stream>>>(kC, 4,
        xbf, 0, 2097152, kC, WqT, 0, 1048576, kC,
        qpart, 1048576, 0, 524288, kC, 0, 0, 1.f, nullptr);
    hgemm_nt<1, 0, 0><<<dim3(16, 16, 2), 256, 0, stream>>>(kC, 1,
        xbf, 0, 2097152, kC, WkvT, 0, 2097152, kC,
        kvh, 0, 0, 4194304, kC2, 0, 0, 1.f, nullptr);

    // Phase 3: V^T + norms (q-norm fuses the split-K reduce)
    transpose_h<_Float16><<<dim3(32, 64, 2), 256, 0, stream>>>(kvh + kC, nullptr,
        4194304, kC2, vT, 2097152, kN2);
    headnorm_q<<<2048, 256, 0, stream>>>(qpart, qn);
    headnorm_kv<<<16384, 256, 0, stream>>>(kvh, kn, vn);

    // Phase 4: v-v similarity (head-sum/8), z=2, SK=2 -> partials
    hgemm_nt<0, 0, 0><<<dim3(16, 4, 4), 256, 0, stream>>>(kC, 2,
        vn, 0, 2097152, kC, vn, 0, 2097152, kC,
        simPart, 2097152, 0, 1048576, kN2, 0, 0, 0.125f, nullptr);

    // Phase 5: scores merged z=16 (0-7 cls w/ colScale, 8-15 reg) -> fp16
    hgemm_nt<1, 2, 0><<<dim3(16, 4, 16), 256, 0, stream>>>(kHD, 1,
        qn, 128, 524288, kC, kn, 128, 2097152, kC,
        S16, 0, 1048576, 8388608, kN2, 7, 3, 25.f, cls_score);

    // Phase 6: fused dual softmax + blend + head-mean + round2 (+ v-sim reduce)
    sb2_kernel<<<512, 256, 0, stream>>>(S16, simPart, attn_h, w_c, w_r);

    // Phase 7: attn @ V with h = blockIdx.x, z=2(g), SK=4 -> partials
    hgemm_nt<0, 0, 1><<<dim3(8, 4, 8), 256, 0, stream>>>(kN2, 4,
        attn_h, 1048576, 0, kN2, vT, 0, 2097152, kN2,
        xcatPart, 1048576, 0, 524288, kC, 0, 0, 1.f, nullptr);
    build_xcat<<<8192, 256, 0, stream>>>(xcatPart, kvh, xcat16);

    // Phase 8: output linears, z=2, SK=2 -> partials
    hgemm_nt<0, 0, 0><<<dim3(16, 4, 4), 256, 0, stream>>>(kC2, 2,
        xcat16, 0, 1048576, kC2, WlinT, 0, 4194304, kC2,
        outPart, 2097152, 0, 1048576, kC2, 0, 0, 1.f, nullptr);

    // Phase 9: ave = w_g @ vT_g^T (plain GEMM, no head logic), z=2, SK=4
    hgemm_nt<0, 0, 0><<<dim3(8, 4, 8), 256, 0, stream>>>(kN2, 4,
        w_c, 0, 1048576, kN2, vT, 0, 2097152, kN2,
        avePart, 1048576, 0, 524288, kC, 0, 0, 1.f, nullptr);

    // Phase 10: write d_out (ave + out-lin reduces + bias)
    finalize<<<12288, 256, 0, stream>>>(avePart, outPart, b_lin, b_lin_reg, out);
}